// Round 5
// baseline (251.021 us; speedup 1.0000x reference)
//
#include <hip/hip_runtime.h>
#include <hip/hip_bf16.h>
#include <cmath>

// ---------------------------------------------------------------------------
// NPerTokenSwishGLU_Basis — fused f16-MFMA implementation (gfx950), round 12.
//
// R8-R11 post-mortem: four nulls (occupancy/barriers/layout/I-cache) at
// grid=512 -> exactly 2 barrier-correlated blocks/CU; R9 showed total cycles
// are work-proportional with no pipe >30% busy -> stalls are correlated
// within the only 2 wave-groups/CU. Geometry (16f x 16l) is rigid; the free
// split is by MATRIX: R12 up_split = 1024 blocks (mh x 8 lg x 64 ft), each
// handling one of {gate, up}: half the work/LDS per block -> 4 independent
// blocks/CU (LDS 38.4KB, __launch_bounds__(256,4) -> 128 VGPR cap).
// silu combine is factored: mh=0 writes U2=us*u' (f16), mh=1 writes
// S=silu(vs*v') (f16); down computes hf = S*U2 in-register (pk_mul_f16).
// Workspace remap: P3 -> 17MiB (dead P2 slot after Np), XA 32, U2 34, S 38.
// ---------------------------------------------------------------------------

typedef _Float16 half8 __attribute__((ext_vector_type(8)));
typedef _Float16 half4 __attribute__((ext_vector_type(4)));
typedef float    f32x4 __attribute__((ext_vector_type(4)));

#define MFMA_F16 __builtin_amdgcn_mfma_f32_16x16x32_f16

static constexpr size_t OFF_P1  = 0;            // 16 MiB; Rp overlay (down)
static constexpr size_t OFF_P2  = 16777216;     // 16 MiB; Np overlay (down, 1 MiB)
static constexpr size_t OFF_P3n = 17825792;     // 16 MiB at 17 MiB (after Np)
static constexpr size_t OFF_XA  = 33554432;     // 2 MiB at 32 MiB
static constexpr size_t OFF_U2  = 35651584;     // 4 MiB at 34 MiB
static constexpr size_t OFF_S   = 39845888;     // 4 MiB at 38 MiB (top 42 MiB)
static constexpr size_t WS_FAST = 54525952;     // 52 MiB (proven)

// ---------------------------------------------------------------------------
// prep (two-sided coalesced transpose), z in {0,1,2} via zoff + blockIdx.y:
//   z=0,1: wg/wu (K,512,1024)=[k][d][f] -> P[f][d][k]
//   z=2  : wd    (K,1024,512)=[k][f][d] -> P3[d][f][k]
// ---------------------------------------------------------------------------
__global__ __launch_bounds__(256) void prep_basis_all(
    const float* __restrict__ wg, const float* __restrict__ wu,
    const float* __restrict__ wd,
    _Float16* __restrict__ P1, _Float16* __restrict__ P2,
    _Float16* __restrict__ P3, int zoff)
{
    int z = blockIdx.y + zoff;
    const float* src = (z == 0) ? wg : (z == 1) ? wu : wd;
    _Float16*    dst = (z == 0) ? P1 : (z == 1) ? P2 : P3;
    int Amin = (z == 2) ? 1024 : 512;    // minor-dim size
    int Bmaj = (z == 2) ? 512 : 1024;    // major-dim size
    int nM = Bmaj >> 4;
    int m0 = (blockIdx.x / nM) * 32;     // minor base
    int M0 = (blockIdx.x % nM) * 16;     // major base

    __shared__ float Sh[16 * 544];       // [k][minor*17 + major]
    int t = threadIdx.x;

    int row = (t >> 2) & 31;
    int cg  = t & 3;
    int khi = t >> 7;
#pragma unroll
    for (int p = 0; p < 8; ++p) {
        int k = p * 2 + khi;
        f32x4 v = *(const f32x4*)(
            src + (size_t)k * Amin * Bmaj + (size_t)(m0 + row) * Bmaj + M0 + cg * 4);
#pragma unroll
        for (int j = 0; j < 4; ++j)
            Sh[k * 544 + row * 17 + cg * 4 + j] = v[j];
    }
    __syncthreads();

    int mn = t & 31, mjb = t >> 5;
#pragma unroll
    for (int q = 0; q < 2; ++q) {
        int mj = mjb + q * 8;
        half8 v0, v1;
#pragma unroll
        for (int k = 0; k < 8; ++k) v0[k] = (_Float16)Sh[k * 544 + mn * 17 + mj];
#pragma unroll
        for (int k = 0; k < 8; ++k) v1[k] = (_Float16)Sh[(k + 8) * 544 + mn * 17 + mj];
        _Float16* out = dst + ((size_t)(M0 + mj) * Amin + m0 + mn) * 16;
        *(half8*)out       = v0;
        *(half8*)(out + 8) = v1;
    }
}

// ---------------------------------------------------------------------------
// prep_x: x fp32 [b][l][d] -> XA f16 [l][d>>3][b][8]
// grid 256 = 128 l x 2 b-halves, 256 threads.
// ---------------------------------------------------------------------------
__global__ __launch_bounds__(256) void prep_x(
    const float* __restrict__ x, _Float16* __restrict__ XA)
{
    int l = blockIdx.x >> 1, bh = blockIdx.x & 1;
    __shared__ __align__(16) _Float16 XT[8][524];
    int t = threadIdx.x;

    int bl = t >> 5, q = t & 31;          // b-local 0..7, q 0..31
    int b = bh * 8 + bl;
#pragma unroll
    for (int j = 0; j < 4; ++j) {
        f32x4 v = *(const f32x4*)(x + ((size_t)(b * 128 + l) * 512 + j * 128 + q * 4));
#pragma unroll
        for (int i = 0; i < 4; ++i)
            XT[bl][j * 128 + q * 4 + i] = (_Float16)v[i];
    }
    __syncthreads();

    int c = t >> 2, bi = t & 3;           // c 0..63
#pragma unroll
    for (int s = 0; s < 2; ++s) {
        int blw = bi * 2 + s;             // 0..7
        half8 h = *(const half8*)(&XT[blw][c * 8]);
        *(half8*)(XA + (((size_t)(l * 64 + c) * 16 + bh * 8 + blw) * 8)) = h;
    }
}

// ---------------------------------------------------------------------------
// up_split (R12): 1024 blocks = mh(2) x 8 lg x 64 f-tiles, 256 thr / 4 waves.
// Each block handles ONE matrix (mh=0: gate -> U2 = us*u'; mh=1: up ->
// S = silu(vs*v')). Dbuf Wt, one barrier/iter, rolled loop.
// LDS: Wt[2][16*584] = 37376 B + CN 1024 B -> 4 blocks/CU.
// __launch_bounds__(256,4): VGPR cap 128 (2048/(4blk*4waves)).
// ---------------------------------------------------------------------------
__global__ __launch_bounds__(256, 4) void up_split(
    const _Float16* __restrict__ P1, const _Float16* __restrict__ P2,
    const _Float16* __restrict__ XA,
    const float* __restrict__ tc1, const float* __restrict__ tc2,
    const float* __restrict__ usp, const float* __restrict__ vsp,
    _Float16* __restrict__ U2, _Float16* __restrict__ S)
{
    int bid = blockIdx.x;
    int mh = bid >> 9;                  // 0: gate/u, 1: up/v
    int lg = (bid >> 6) & 7;
    int f0 = (bid & 63) * 16;
    int tid = threadIdx.x;
    int w = tid >> 6, lane = tid & 63;
    int n = lane & 15, kc = lane >> 4;
    bool ldp = (kc < 2);

    const _Float16* P  = mh ? P2 : P1;
    const float*    tc = mh ? tc2 : tc1;

    __shared__ __align__(16) _Float16 Wt[2][16 * 584]; // [buf][l*584+f*36+d]
    __shared__ float CN[256];

    // element-unit base pointers (advance +512 per 32-d chunk)
    const _Float16* pP  = P + ((size_t)(f0 + w * 4) * 512 + n) * 16 + kc * 8;
    const _Float16* pXA = XA + (((size_t)(lg * 16 + w * 4) * 64 + kc) * 16 + n) * 8;

    half8 pa[4][2];
    // ---- prologue: issue pa(0); softmax + barrier cover the latency ----
#pragma unroll
    for (int fl = 0; fl < 4; ++fl)
#pragma unroll
        for (int dg = 0; dg < 2; ++dg) {
            half8 a = { 0, 0, 0, 0, 0, 0, 0, 0 };
            if (ldp) a = *(const half8*)(pP + fl * 8192 + dg * 256);
            pa[fl][dg] = a;
        }
    const _Float16* qP = pP + 512;

    if (tid < 16) {
        const float* row = tc + (size_t)(lg * 16 + tid) * 16;
        float e[16], m = -1e30f, sum = 0.f;
#pragma unroll
        for (int k = 0; k < 16; ++k) m = fmaxf(m, row[k]);
#pragma unroll
        for (int k = 0; k < 16; ++k) { e[k] = __expf(row[k] - m); sum += e[k]; }
        float r = 1.f / sum;
#pragma unroll
        for (int k = 0; k < 16; ++k) CN[tid * 16 + k] = e[k] * r;
    }
    __syncthreads();

    half8 cf = { 0, 0, 0, 0, 0, 0, 0, 0 };
    if (ldp) {
#pragma unroll
        for (int j = 0; j < 8; ++j)
            cf[j] = (_Float16)CN[n * 16 + kc * 8 + j];
    }

    f32x4 zf = { 0.f, 0.f, 0.f, 0.f };
    f32x4 aU[4];
#pragma unroll
    for (int i = 0; i < 4; ++i) aU[i] = zf;
    float nsq[4] = { 0.f, 0.f, 0.f, 0.f };
    half8 xf[4];

#pragma unroll 1
    for (int it = 0; it < 16; ++it) {
        _Float16* WtW = &Wt[it & 1][0];
        const _Float16* WtR = &Wt[(it & 1) ^ 1][0];

        // ---- mix(it) (pa drained at previous barrier) ----
#pragma unroll
        for (int fl = 0; fl < 4; ++fl) {
            int f_l = w * 4 + fl;
#pragma unroll
            for (int dg = 0; dg < 2; ++dg) {
                f32x4 c1 = MFMA_F16(pa[fl][dg], cf, zf, 0, 0, 0);
                nsq[fl] += c1[0] * c1[0] + c1[1] * c1[1]
                         + c1[2] * c1[2] + c1[3] * c1[3];
                half4 h1 = { (_Float16)c1[0], (_Float16)c1[1],
                             (_Float16)c1[2], (_Float16)c1[3] };
                *(half4*)(&WtW[n * 584 + f_l * 36 + dg * 16 + kc * 4]) = h1;
            }
        }
        // ---- issue pa(it+1) into freed regs ----
        if (it < 15) {
#pragma unroll
            for (int fl = 0; fl < 4; ++fl)
#pragma unroll
                for (int dg = 0; dg < 2; ++dg) {
                    half8 a = { 0, 0, 0, 0, 0, 0, 0, 0 };
                    if (ldp) a = *(const half8*)(qP + fl * 8192 + dg * 256);
                    pa[fl][dg] = a;
                }
        }
        // ---- consume(it-1) from the other buffer ----
        if (it > 0) {
#pragma unroll
            for (int li = 0; li < 4; ++li) {
                int l = w * 4 + li;
                half8 wU = *(const half8*)(&WtR[l * 584 + n * 36 + kc * 8]);
                aU[li] = MFMA_F16(xf[li], wU, aU[li], 0, 0, 0);
            }
        }
        // ---- load xf(it): 1KB dense per wave ----
#pragma unroll
        for (int li = 0; li < 4; ++li)
            xf[li] = *(const half8*)(pXA + li * 8192);
        pXA += 512;
        qP += 512;
        __syncthreads();
    }
    // ---- tail consume (chunk 15, buffer 1) ----
#pragma unroll
    for (int li = 0; li < 4; ++li) {
        int l = w * 4 + li;
        half8 wU = *(const half8*)(&Wt[1][l * 584 + n * 36 + kc * 8]);
        aU[li] = MFMA_F16(xf[li], wU, aU[li], 0, 0, 0);
    }

    // ---- norm reduce ----
#pragma unroll
    for (int fl = 0; fl < 4; ++fl) {
        float vU = nsq[fl];
        vU += __shfl_xor(vU, 16); vU += __shfl_xor(vU, 32);
        if (kc == 0) CN[n * 16 + w * 4 + fl] = vU;
    }
    __syncthreads();

    int f = f0 + n;
    float sc = mh ? (fabsf(vsp[f]) * 22.627416997969522f)   // vs = |vsp|*sqrt(512)
                  : fabsf(usp[f]);                          // us = |usp|
    _Float16* Out = mh ? S : U2;
#pragma unroll
    for (int li = 0; li < 4; ++li) {
        int lgl = lg * 16 + w * 4 + li;
        float r1 = 1.f / fmaxf(sqrtf(CN[(w * 4 + li) * 16 + n]), 1e-12f);
#pragma unroll
        for (int i = 0; i < 4; ++i) {
            float val = aU[li][i] * r1 * sc;       // us*u'  or  vs*v'
            if (mh) val = val / (1.f + __expf(-val));   // silu(vs*v')
            // layout [l][f>>3][b][8]
            Out[(((size_t)lgl * 128 + (f >> 3)) * 16 + kc * 4 + i) * 8 + (f & 7)] =
                (_Float16)val;
        }
    }
}

// ---------------------------------------------------------------------------
// down_fast (R12): 1024 blocks = 4 f-quarters x 8 lg x 32 d-tiles.
// hf = S-tile * U2-tile (in-register pk_mul_f16); otherwise R11 structure.
// ---------------------------------------------------------------------------
__global__ __launch_bounds__(256, 2) void down_fast(
    const _Float16* __restrict__ P3, const float* __restrict__ tc3,
    const _Float16* __restrict__ S, const _Float16* __restrict__ U2,
    float* __restrict__ Rp, float* __restrict__ Np)
{
    int zh = blockIdx.x >> 8;          // 0..3
    int rem = blockIdx.x & 255;
    int lg = rem >> 5;
    int d0 = (rem & 31) * 16;
    int tid = threadIdx.x;
    int w = tid >> 6, lane = tid & 63;
    int n = lane & 15, kc = lane >> 4;
    bool ldp = (kc < 2);

    __shared__ __align__(16) _Float16 Wt[2][16 * 584];    // [buf][l*584 + d*36 + f]
    __shared__ float CN[256];

    // element-unit base pointers (advance +512 per 32-f chunk)
    const _Float16* pP3 = P3 + ((size_t)(d0 + w * 4) * 1024 + zh * 256 + n) * 16 + kc * 8;
    size_t hoff = (((size_t)(lg * 16 + w * 4) * 128 + zh * 32 + kc) * 16 + n) * 8;
    const _Float16* pS = S + hoff;
    const _Float16* pU = U2 + hoff;

    half8 pa[4][2];
    // ---- prologue: issue pa(0) ----
#pragma unroll
    for (int dl = 0; dl < 4; ++dl)
#pragma unroll
        for (int fg = 0; fg < 2; ++fg) {
            half8 a = { 0, 0, 0, 0, 0, 0, 0, 0 };
            if (ldp) a = *(const half8*)(pP3 + dl * 16384 + fg * 256);
            pa[dl][fg] = a;
        }
    const _Float16* qP3 = pP3 + 512;

    if (tid < 16) {
        const float* row = tc3 + (size_t)(lg * 16 + tid) * 16;
        float e[16], m = -1e30f, sum = 0.f;
#pragma unroll
        for (int k = 0; k < 16; ++k) m = fmaxf(m, row[k]);
#pragma unroll
        for (int k = 0; k < 16; ++k) { e[k] = __expf(row[k] - m); sum += e[k]; }
        float r = 1.f / sum;
#pragma unroll
        for (int k = 0; k < 16; ++k) CN[tid * 16 + k] = e[k] * r;
    }
    __syncthreads();

    half8 cf3 = { 0, 0, 0, 0, 0, 0, 0, 0 };
    if (ldp) {
#pragma unroll
        for (int j = 0; j < 8; ++j)
            cf3[j] = (_Float16)CN[n * 16 + kc * 8 + j];
    }

    f32x4 zf = { 0.f, 0.f, 0.f, 0.f };
    f32x4 aO[4];
#pragma unroll
    for (int i = 0; i < 4; ++i) aO[i] = zf;
    float nsqD[4] = { 0.f, 0.f, 0.f, 0.f };
    half8 hf[4];

#pragma unroll 1
    for (int it = 0; it < 8; ++it) {
        _Float16* WtW = &Wt[it & 1][0];
        const _Float16* WtR = &Wt[(it & 1) ^ 1][0];

        // ---- mix(it) ----
#pragma unroll
        for (int dl = 0; dl < 4; ++dl) {
            int d_l = w * 4 + dl;
#pragma unroll
            for (int fg = 0; fg < 2; ++fg) {
                f32x4 cw = MFMA_F16(pa[dl][fg], cf3, zf, 0, 0, 0);
                nsqD[dl] += cw[0] * cw[0] + cw[1] * cw[1]
                          + cw[2] * cw[2] + cw[3] * cw[3];
                half4 h4 = { (_Float16)cw[0], (_Float16)cw[1],
                             (_Float16)cw[2], (_Float16)cw[3] };
                *(half4*)(&WtW[n * 584 + d_l * 36 + fg * 16 + kc * 4]) = h4;
            }
        }
        // ---- issue pa(it+1) ----
        if (it < 7) {
#pragma unroll
            for (int dl = 0; dl < 4; ++dl)
#pragma unroll
                for (int fg = 0; fg < 2; ++fg) {
                    half8 a = { 0, 0, 0, 0, 0, 0, 0, 0 };
                    if (ldp) a = *(const half8*)(qP3 + dl * 16384 + fg * 256);
                    pa[dl][fg] = a;
                }
        }
        // ---- consume(it-1) ----
        if (it > 0) {
#pragma unroll
            for (int li = 0; li < 4; ++li) {
                int l = w * 4 + li;
                half8 wf = *(const half8*)(&WtR[l * 584 + n * 36 + kc * 8]);
                aO[li] = MFMA_F16(hf[li], wf, aO[li], 0, 0, 0);
            }
        }
        // ---- load hf(it) = S * U2 (each 1KB dense per wave) ----
#pragma unroll
        for (int li = 0; li < 4; ++li) {
            half8 s8 = *(const half8*)(pS + li * 16384);
            half8 u8 = *(const half8*)(pU + li * 16384);
            hf[li] = s8 * u8;
        }
        pS += 512;
        pU += 512;
        qP3 += 512;
        __syncthreads();
    }
    // ---- tail consume (chunk 7, buffer 1) ----
#pragma unroll
    for (int li = 0; li < 4; ++li) {
        int l = w * 4 + li;
        half8 wf = *(const half8*)(&Wt[1][l * 584 + n * 36 + kc * 8]);
        aO[li] = MFMA_F16(hf[li], wf, aO[li], 0, 0, 0);
    }

#pragma unroll
    for (int dl = 0; dl < 4; ++dl) {
        float v = nsqD[dl];
        v += __shfl_xor(v, 16); v += __shfl_xor(v, 32);
        if (kc == 0)
            Np[(size_t)zh * 65536 + (size_t)(lg * 16 + n) * 512 + d0 + w * 4 + dl] = v;
    }
#pragma unroll
    for (int li = 0; li < 4; ++li) {
        int lgl = lg * 16 + w * 4 + li;
#pragma unroll
        for (int i = 0; i < 4; ++i)
            Rp[(size_t)zh * 1048576 +
               ((size_t)(kc * 4 + i) * 128 + lgl) * 512 + d0 + n] = aO[li][i];
    }
}

// ---------------------------------------------------------------------------
__global__ __launch_bounds__(128) void final_combine(
    const float* __restrict__ Rp, const float* __restrict__ Np,
    float* __restrict__ out)
{
    int rid = blockIdx.x;              // b*128 + l
    int l = rid & 127;
    int t = threadIdx.x;
    f32x4 r = { 0.f, 0.f, 0.f, 0.f };
    f32x4 nn = { 0.f, 0.f, 0.f, 0.f };
#pragma unroll
    for (int zh = 0; zh < 4; ++zh) {
        f32x4 rz = *(const f32x4*)(Rp + (size_t)zh * 1048576 + (size_t)rid * 512 + t * 4);
        f32x4 nz = *(const f32x4*)(Np + (size_t)zh * 65536 + (size_t)l * 512 + t * 4);
#pragma unroll
        for (int j = 0; j < 4; ++j) { r[j] += rz[j]; nn[j] += nz[j]; }
    }
    f32x4 y;
#pragma unroll
    for (int j = 0; j < 4; ++j) {
        float rr = 1.f / fmaxf(sqrtf(fmaxf(nn[j], 0.f)), 1e-12f);
        y[j] = r[j] * rr;
    }
    float s = y[0] * y[0] + y[1] * y[1] + y[2] * y[2] + y[3] * y[3];
#pragma unroll
    for (int off = 32; off > 0; off >>= 1) s += __shfl_down(s, off);
    __shared__ float sred[2];
    if ((t & 63) == 0) sred[t >> 6] = s;
    __syncthreads();
    float rr = 1.f / fmaxf(sqrtf(sred[0] + sred[1]), 1e-12f);
    f32x4 o = { y[0] * rr, y[1] * rr, y[2] * rr, y[3] * rr };
    *(f32x4*)(out + (size_t)rid * 512 + t * 4) = o;
}

// ===========================================================================
// SLOW FALLBACK (round-2 kernels, proven) — used when ws_size < WS_FAST
// ===========================================================================
__global__ __launch_bounds__(256) void up_kernel(
    const float* __restrict__ x,
    const float* __restrict__ wg, const float* __restrict__ wu,
    const float* __restrict__ tc1, const float* __restrict__ tc2,
    const float* __restrict__ usp, const float* __restrict__ vsp,
    _Float16* __restrict__ Hp)
{
    int lg = blockIdx.x >> 6;
    int f0 = (blockIdx.x & 63) * 16;
    int tid = threadIdx.x;
    int w = tid >> 6, lane = tid & 63;
    int n = lane & 15, kc = lane >> 4;

    __shared__ __align__(16) _Float16 Xt[256 * 40];
    __shared__ __align__(16) _Float16 Bh[32 * 16 * 24];
    __shared__ __align__(16) _Float16 Wt[16 * 528];
    __shared__ float CN[2 * 16 * 16];

    if (tid < 32) {
        int s = tid >> 4, ll = tid & 15;
        const float* row = (s ? tc2 : tc1) + (size_t)(lg * 16 + ll) * 16;
        float e[16], m = -1e30f, sum = 0.f;
#pragma unroll
        for (int k = 0; k < 16; ++k) m = fmaxf(m, row[k]);
#pragma unroll
        for (int k = 0; k < 16; ++k) { e[k] = __expf(row[k] - m); sum += e[k]; }
        float r = 1.f / sum;
#pragma unroll
        for (int k = 0; k < 16; ++k) CN[s * 256 + ll * 16 + k] = e[k] * r;
    }
    __syncthreads();

    half8 cf1 = { 0, 0, 0, 0, 0, 0, 0, 0 };
    half8 cf2 = { 0, 0, 0, 0, 0, 0, 0, 0 };
    if (kc < 2) {
#pragma unroll
        for (int j = 0; j < 8; ++j) {
            cf1[j] = (_Float16)CN[0 * 256 + n * 16 + kc * 8 + j];
            cf2[j] = (_Float16)CN[1 * 256 + n * 16 + kc * 8 + j];
        }
    }

    f32x4 zf = { 0.f, 0.f, 0.f, 0.f };
    f32x4 aU[4], aV[4];
#pragma unroll
    for (int i = 0; i < 4; ++i) { aU[i] = zf; aV[i] = zf; }
    float nsqU[4] = { 0.f, 0.f, 0.f, 0.f };
    float nsqV[4] = { 0.f, 0.f, 0.f, 0.f };

    for (int it = 0; it < 16; ++it) {
        int d0 = it * 32;
#pragma unroll
        for (int p = 0; p < 8; ++p) {
            int r = p * 32 + (tid >> 3);
            int fj = tid & 7;
            int ll = r >> 4, b = r & 15;
            f32x4 v = *(const f32x4*)(
                x + ((size_t)(b * 128 + lg * 16 + ll) * 512 + d0 + fj * 4));
            half4 h = { (_Float16)v[0], (_Float16)v[1],
                        (_Float16)v[2], (_Float16)v[3] };
            *(half4*)(&Xt[r * 40 + fj * 4]) = h;
        }
#pragma unroll
        for (int p = 0; p < 8; ++p) {
            int idx = p * 256 + tid;
            int q = idx & 3, dd = (idx >> 2) & 31, k = idx >> 7;
            f32x4 v = *(const f32x4*)(
                wg + ((size_t)k * 512 + d0 + dd) * 1024 + f0 + q * 4);
#pragma unroll
            for (int j = 0; j < 4; ++j)
                Bh[(dd * 16 + q * 4 + j) * 24 + k] = (_Float16)v[j];
        }
        __syncthreads();
#pragma unroll
        for (int fl = 0; fl < 4; ++fl) {
            int f_l = w * 4 + fl;
#pragma unroll
            for (int dg = 0; dg < 2; ++dg) {
                half8 a = { 0, 0, 0, 0, 0, 0, 0, 0 };
                if (kc < 2)
                    a = *(const half8*)(&Bh[((dg * 16 + n) * 16 + f_l) * 24 + kc * 8]);
                f32x4 cw = MFMA_F16(a, cf1, zf, 0, 0, 0);
                nsqU[fl] += cw[0] * cw[0] + cw[1] * cw[1]
                          + cw[2] * cw[2] + cw[3] * cw[3];
                half4 h4 = { (_Float16)cw[0], (_Float16)cw[1],
                             (_Float16)cw[2], (_Float16)cw[3] };
                *(half4*)(&Wt[n * 528 + f_l * 32 + dg * 16 + kc * 4]) = h4;
            }
        }
        __syncthreads();
#pragma unroll
        for (int li = 0; li < 4; ++li) {
            int l = w * 4 + li;
            half8 xf = *(const half8*)(&Xt[(l * 16 + n) * 40 + kc * 8]);
            half8 wf = *(const half8*)(&Wt[l * 528 + n * 32 + kc * 8]);
            aU[li] = MFMA_F16(xf, wf, aU[li], 0, 0, 0);
        }
#pragma unroll
        for (int p = 0; p < 8; ++p) {
            int idx = p * 256 + tid;
            int q = idx & 3, dd = (idx >> 2) & 31, k = idx >> 7;
            f32x4 v = *(const f32x4*)(
                wu + ((size_t)k * 512 + d0 + dd) * 1024 + f0 + q * 4);
#pragma unroll
            for (int j = 0; j < 4; ++j)
                Bh[(dd * 16 + q * 4 + j) * 24 + k] = (_Float16)v[j];
        }
        __syncthreads();
#pragma unroll
        for (int fl = 0; fl < 4; ++fl) {
            int f_l = w * 4 + fl;
#pragma unroll
            for (int dg = 0; dg < 2; ++dg) {
                half8 a = { 0, 0, 0, 0, 0, 0, 0, 0 };
                if (kc < 2)
                    a = *(const half8*)(&Bh[((dg * 16 + n) * 16 + f_l) * 24 + kc * 8]);
                f32x4 cw = MFMA_F16(a, cf2, zf, 0, 0, 0);
                nsqV[fl] += cw[0] * cw[0] + cw[1] * cw[1]
                          + cw[2] * cw[2] + cw[3] * cw[3];
                half4 h4 = { (_Float16)cw[0], (_Float16)cw[1],
                             (_Float16)cw[2], (_Float16)cw[3] };
                *(half4*)(&Wt[n * 528 + f_l * 32 + dg * 16 + kc * 4]) = h4;
            }
        }
        __syncthreads();
#pragma unroll
        for (int li = 0; li < 4; ++li) {
            int l = w * 4 + li;
            half8 xf = *(const half8*)(&Xt[(l * 16 + n) * 40 + kc * 8]);
            half8 wf = *(const half8*)(&Wt[l * 528 + n * 32 + kc * 8]);
            aV[li] = MFMA_F16(xf, wf, aV[li], 0, 0, 0);
        }
        __syncthreads();
    }

#pragma unroll
    for (int fl = 0; fl < 4; ++fl) {
        float vU = nsqU[fl], vV = nsqV[fl];
        vU += __shfl_xor(vU, 16); vU += __shfl_xor(vU, 32);
        vV += __shfl_xor(vV, 16); vV += __shfl_xor(vV, 32);
        if (kc == 0) {
            CN[0 * 256 + n * 16 + w * 4 + fl] = vU;
            CN[1 * 256 + n * 16 + w * 4 + fl] = vV;
        }
    }
    __syncthreads();

    int f = f0 + n;
    float usv = fabsf(usp[f]);
    float vsv = fabsf(vsp[f]) * 22.627416997969522f;
#pragma unroll
    for (int li = 0; li < 4; ++li) {
        int lgl = lg * 16 + w * 4 + li;
        float r1 = 1.f / fmaxf(sqrtf(CN[0 * 256 + (w * 4 + li) * 16 + n]), 1e-12f);
        float r2 = 1.f / fmaxf(sqrtf(CN[1 * 256 + (w * 4 + li) * 16 + n]), 1e-12f);
#pragma unroll
        for (int i = 0; i < 4; ++i) {
            float u = aU[li][i] * r1;
            float v = aV[li][i] * r2;
            float zz = vsv * v;
            float sil = zz / (1.f + __expf(-zz));
            float h = sil * (usv * u);
            Hp[((size_t)lgl * 16 + kc * 4 + i) * 1024 + f] = (_Float16)h;
        }
    }
}

__global__ __launch_bounds__(256) void down_kernel(
    const float* __restrict__ wd, const float* __restrict__ tc3,
    const _Float16* __restrict__ Hp, float* __restrict__ out)
{
    int lg = blockIdx.x >> 5;
    int d0 = (blockIdx.x & 31) * 16;
    int tid = threadIdx.x;
    int w = tid >> 6, lane = tid & 63;
    int n = lane & 15, kc = lane >> 4;

    __shared__ __align__(16) _Float16 Ht[256 * 40];
    __shared__ __align__(16) _Float16 Bh[32 * 16 * 24];
    __shared__ __align__(16) _Float16 Wt[16 * 528];
    __shared__ float CN[16 * 16];

    if (tid < 16) {
        const float* row = tc3 + (size_t)(lg * 16 + tid) * 16;
        float e[16], m = -1e30f, sum = 0.f;
#pragma unroll
        for (int k = 0; k < 16; ++k) m = fmaxf(m, row[k]);
#pragma unroll
        for (int k = 0; k < 16; ++k) { e[k] = __expf(row[k] - m); sum += e[k]; }
        float r = 1.f / sum;
#pragma unroll
        for (int k = 0; k < 16; ++k) CN[tid * 16 + k] = e[k] * r;
    }
    __syncthreads();

    half8 cf3 = { 0, 0, 0, 0, 0, 0, 0, 0 };
    if (kc < 2) {
#pragma unroll
        for (int j = 0; j < 8; ++j)
            cf3[j] = (_Float16)CN[n * 16 + kc * 8 + j];
    }

    f32x4 zf = { 0.f, 0.f, 0.f, 0.f };
    f32x4 aO[4];
#pragma unroll
    for (int i = 0; i < 4; ++i) aO[i] = zf;
    float nsqD[4] = { 0.f, 0.f, 0.f, 0.f };

    for (int it = 0; it < 32; ++it) {
        int f0 = it * 32;
#pragma unroll
        for (int p = 0; p < 8; ++p) {
            int r = p * 32 + (tid >> 3);
            int hj = tid & 7;
            int ll = r >> 4, b = r & 15;
            half4 v = *(const half4*)(
                Hp + ((size_t)(lg * 16 + ll) * 16 + b) * 1024 + f0 + hj * 4);
            *(half4*)(&Ht[r * 40 + hj * 4]) = v;
        }
#pragma unroll
        for (int p = 0; p < 8; ++p) {
            int idx = p * 256 + tid;
            int q = idx & 3, ff = (idx >> 2) & 31, k = idx >> 7;
            f32x4 v = *(const f32x4*)(
                wd + ((size_t)k * 1024 + f0 + ff) * 512 + d0 + q * 4);
#pragma unroll
            for (int j = 0; j < 4; ++j)
                Bh[(ff * 16 + q * 4 + j) * 24 + k] = (_Float16)v[j];
        }
        __syncthreads();
#pragma unroll
        for (int dl = 0; dl < 4; ++dl) {
            int d_l = w * 4 + dl;
#pragma unroll
            for (int fg = 0; fg < 2; ++fg) {
                half8 a = { 0, 0, 0, 0, 0, 0, 0, 0 };
                if (kc < 2)
                    a = *(const half8*)(&Bh[((fg * 16 + n) * 16 + d_l) * 24 + kc * 8]);
                f32x4 cw = MFMA_F16(a, cf3, zf, 0, 0, 0);
                nsqD[dl] += cw[0] * cw[0] + cw[1] * cw[1]
                          + cw[2] * cw[2] + cw[3] * cw[3];
                half4 h4 = { (_Float16)cw[0], (_Float16)cw[1],
                             (_Float16)cw[2], (_Float16)cw[3] };
                *(half4*)(&Wt[n * 528 + d_l * 32 + fg * 16 + kc * 4]) = h4;
            }
        }
        __syncthreads();
#pragma unroll
        for (int li = 0; li < 4; ++li) {
            int l = w * 4 + li;
            half8 hf = *(const half8*)(&Ht[(l * 16 + n) * 40 + kc * 8]);
            half8 wf = *(const half8*)(&Wt[l * 528 + n * 32 + kc * 8]);
            aO[li] = MFMA_F16(hf, wf, aO[li], 0, 0, 0);
        }
        __syncthreads();
    }

#pragma unroll
    for (int dl = 0; dl < 4; ++dl) {
        float v = nsqD[dl];
        v += __shfl_xor(v, 16); v += __shfl_xor(v, 32);
        if (kc == 0) CN[n * 16 + w * 4 + dl] = v;
    }
    __syncthreads();

#pragma unroll
    for (int li = 0; li < 4; ++li) {
        int lgl = lg * 16 + w * 4 + li;
        float r3 = 1.f / fmaxf(sqrtf(CN[(w * 4 + li) * 16 + n]), 1e-12f);
#pragma unroll
        for (int i = 0; i < 4; ++i)
            out[((size_t)(kc * 4 + i) * 128 + lgl) * 512 + d0 + n] = aO[li][i] * r3;
    }
}

__global__ __launch_bounds__(128) void final_kernel(float* __restrict__ out)
{
    int rid = blockIdx.x;
    int t = threadIdx.x;
    f32x4 y = *(const f32x4*)(out + (size_t)rid * 512 + t * 4);
    float s = y[0] * y[0] + y[1] * y[1] + y[2] * y[2] + y[3] * y[3];
#pragma unroll
    for (int off = 32; off > 0; off >>= 1) s += __shfl_down(s, off);
    __shared__ float sred[2];
    if ((t & 63) == 0) sred[t >> 6] = s;
    __syncthreads();
    float rr = 1.f / fmaxf(sqrtf(sred[0] + sred[1]), 1e-12f);
    f32x4 o = { y[0] * rr, y[1] * rr, y[2] * rr, y[3] * rr };
    *(f32x4*)(out + (size_t)rid * 512 + t * 4) = o;
}

// ---------------------------------------------------------------------------
extern "C" void kernel_launch(void* const* d_in, const int* in_sizes, int n_in,
                              void* d_out, int out_size, void* d_ws, size_t ws_size,
                              hipStream_t stream)
{
    (void)in_sizes; (void)n_in; (void)out_size;
    const float* x   = (const float*)d_in[0];
    const float* wg  = (const float*)d_in[1];
    const float* wu  = (const float*)d_in[2];
    const float* wd  = (const float*)d_in[3];
    const float* tc1 = (const float*)d_in[4];
    const float* tc2 = (const float*)d_in[5];
    const float* tc3 = (const float*)d_in[6];
    const float* usp = (const float*)d_in[7];
    const float* vsp = (const float*)d_in[8];
    float* outp = (float*)d_out;
    char* ws = (char*)d_ws;

    if (ws_size >= WS_FAST) {
        _Float16* P1  = (_Float16*)(ws + OFF_P1);
        _Float16* P2  = (_Float16*)(ws + OFF_P2);
        _Float16* P3n = (_Float16*)(ws + OFF_P3n);  // 17..33 MiB (after Np)
        _Float16* XA  = (_Float16*)(ws + OFF_XA);   // 32..34 MiB (dead before prep3? no:
                                                    //  prep3 covers 17..33; XA dead by then)
        _Float16* U2  = (_Float16*)(ws + OFF_U2);   // 34..38 MiB
        _Float16* S   = (_Float16*)(ws + OFF_S);    // 38..42 MiB
        float* Rp = (float*)(ws + OFF_P1);   // overlays P1 (dead after up)
        float* Np = (float*)(ws + OFF_P2);   // 16..17 MiB (P2 dead after up)
        prep_basis_all<<<dim3(1024, 2), dim3(256), 0, stream>>>(
            wg, wu, wd, P1, P2, P3n, 0);                   // P1, P2
        prep_x<<<dim3(256), dim3(256), 0, stream>>>(x, XA);
        up_split<<<dim3(1024), dim3(256), 0, stream>>>(P1, P2, XA, tc1, tc2,
                                                       usp, vsp, U2, S);
        prep_basis_all<<<dim3(1024, 1), dim3(256), 0, stream>>>(
            wg, wu, wd, P1, P2, P3n, 2);                   // P3 at 17 MiB
        down_fast<<<dim3(1024), dim3(256), 0, stream>>>(P3n, tc3, S, U2, Rp, Np);
        final_combine<<<dim3(2048), dim3(128), 0, stream>>>(Rp, Np, outp);
    } else {
        _Float16* Hp = (_Float16*)ws;
        up_kernel<<<dim3(512), dim3(256), 0, stream>>>(x, wg, wu, tc1, tc2,
                                                       usp, vsp, Hp);
        down_kernel<<<dim3(256), dim3(256), 0, stream>>>(wd, tc3, Hp, outp);
        final_kernel<<<dim3(2048), dim3(128), 0, stream>>>(outp);
    }
}

// Round 6
// 226.194 us; speedup vs baseline: 1.1098x; 1.1098x over previous
//
#include <hip/hip_runtime.h>
#include <hip/hip_bf16.h>
#include <cmath>

// ---------------------------------------------------------------------------
// NPerTokenSwishGLU_Basis — fused f16-MFMA implementation (gfx950), round 13.
//
// R12 post-mortem: mat-split worked (up 57->49.8us, occ 34%) but total
// regressed 244->251 — the other 5 kernels sum to ~200us. R13 fixes:
//  1) prep_basis tile 32x16 -> 32x32 (reads 64B -> 128B granules, LDS
//     stride-34, conflict-free) — preps are ~40% of the pipeline.
//  2) mix MFMA 16x16x32 -> 16x16x16 (K=16 exact, no zero-pad): pa/cf loads
//     become full-64-lane 8B (kc<2 mask gone), mix regs halve. C layout
//     identical -> Wt/nsq indexing unchanged. Same math -> same absmax.
//  3) same mix fix in down_fast.
// ---------------------------------------------------------------------------

typedef _Float16 half8 __attribute__((ext_vector_type(8)));
typedef _Float16 half4 __attribute__((ext_vector_type(4)));
typedef float    f32x4 __attribute__((ext_vector_type(4)));
typedef float    f32x2 __attribute__((ext_vector_type(2)));

#define MFMA_F16  __builtin_amdgcn_mfma_f32_16x16x32_f16
#define MFMA16    __builtin_amdgcn_mfma_f32_16x16x16f16

static constexpr size_t OFF_P1  = 0;            // 16 MiB; Rp overlay (down)
static constexpr size_t OFF_P2  = 16777216;     // 16 MiB; Np overlay (down, 1 MiB)
static constexpr size_t OFF_P3n = 17825792;     // 16 MiB at 17 MiB (after Np)
static constexpr size_t OFF_XA  = 33554432;     // 2 MiB at 32 MiB
static constexpr size_t OFF_U2  = 35651584;     // 4 MiB at 34 MiB
static constexpr size_t OFF_S   = 39845888;     // 4 MiB at 38 MiB (top 42 MiB)
static constexpr size_t WS_FAST = 54525952;     // 52 MiB (proven)

// ---------------------------------------------------------------------------
// prep (two-sided coalesced transpose), 32x32 tiles (R13):
//   z=0,1: wg/wu (K,512,1024)=[k][d][f] -> P[f][d][k]
//   z=2  : wd    (K,1024,512)=[k][f][d] -> P3[d][f][k]
// Reads: 8 lanes x 16B = 128B per row (full L2 line). Writes: 32B/lane dense.
// LDS S[16][32*34] f32 = 69632 B, stride 34 -> <=2-way bank alias (free).
// ---------------------------------------------------------------------------
__global__ __launch_bounds__(256) void prep_basis_all(
    const float* __restrict__ wg, const float* __restrict__ wu,
    const float* __restrict__ wd,
    _Float16* __restrict__ P1, _Float16* __restrict__ P2,
    _Float16* __restrict__ P3, int zoff)
{
    int z = blockIdx.y + zoff;
    const float* src = (z == 0) ? wg : (z == 1) ? wu : wd;
    _Float16*    dst = (z == 0) ? P1 : (z == 1) ? P2 : P3;
    int Amin = (z == 2) ? 1024 : 512;    // minor-dim size
    int Bmaj = (z == 2) ? 512 : 1024;    // major-dim size
    int nM = Bmaj >> 5;
    int m0 = (blockIdx.x / nM) * 32;     // minor base
    int M0 = (blockIdx.x % nM) * 32;     // major base

    __shared__ float S[16 * 1088];       // [k][row*34 + col]
    int t = threadIdx.x;

    int row = t >> 3;                    // 0..31 (minor row)
    int cg  = t & 7;                     // 0..7 (16B col group)
#pragma unroll
    for (int k = 0; k < 16; ++k) {
        f32x4 v = *(const f32x4*)(
            src + (size_t)k * Amin * Bmaj + (size_t)(m0 + row) * Bmaj + M0 + cg * 4);
        f32x2 lo = { v[0], v[1] };
        f32x2 hi = { v[2], v[3] };
        *(f32x2*)(&S[k * 1088 + row * 34 + cg * 4])     = lo;
        *(f32x2*)(&S[k * 1088 + row * 34 + cg * 4 + 2]) = hi;
    }
    __syncthreads();

    int mn = t & 31, mjq = t >> 5;
#pragma unroll
    for (int q = 0; q < 4; ++q) {
        int mj = q * 8 + mjq;
        half8 v0, v1;
#pragma unroll
        for (int k = 0; k < 8; ++k) v0[k] = (_Float16)S[k * 1088 + mn * 34 + mj];
#pragma unroll
        for (int k = 0; k < 8; ++k) v1[k] = (_Float16)S[(k + 8) * 1088 + mn * 34 + mj];
        _Float16* out = dst + ((size_t)(M0 + mj) * Amin + m0 + mn) * 16;
        *(half8*)out       = v0;
        *(half8*)(out + 8) = v1;
    }
}

// ---------------------------------------------------------------------------
// prep_x: x fp32 [b][l][d] -> XA f16 [l][d>>3][b][8]
// grid 256 = 128 l x 2 b-halves, 256 threads.
// ---------------------------------------------------------------------------
__global__ __launch_bounds__(256) void prep_x(
    const float* __restrict__ x, _Float16* __restrict__ XA)
{
    int l = blockIdx.x >> 1, bh = blockIdx.x & 1;
    __shared__ __align__(16) _Float16 XT[8][524];
    int t = threadIdx.x;

    int bl = t >> 5, q = t & 31;          // b-local 0..7, q 0..31
    int b = bh * 8 + bl;
#pragma unroll
    for (int j = 0; j < 4; ++j) {
        f32x4 v = *(const f32x4*)(x + ((size_t)(b * 128 + l) * 512 + j * 128 + q * 4));
#pragma unroll
        for (int i = 0; i < 4; ++i)
            XT[bl][j * 128 + q * 4 + i] = (_Float16)v[i];
    }
    __syncthreads();

    int c = t >> 2, bi = t & 3;           // c 0..63
#pragma unroll
    for (int s = 0; s < 2; ++s) {
        int blw = bi * 2 + s;             // 0..7
        half8 h = *(const half8*)(&XT[blw][c * 8]);
        *(half8*)(XA + (((size_t)(l * 64 + c) * 16 + bh * 8 + blw) * 8)) = h;
    }
}

// ---------------------------------------------------------------------------
// up_split (R13): 1024 blocks = mh(2) x 8 lg x 64 f-tiles, 256 thr / 4 waves.
// Mix uses 16x16x16 MFMA (K=16 exact): pa/cf full-lane 8B loads, no mask.
// LDS: Wt[2][16*584] = 37376 B + CN 1024 B -> 4 blocks/CU.
// ---------------------------------------------------------------------------
__global__ __launch_bounds__(256, 4) void up_split(
    const _Float16* __restrict__ P1, const _Float16* __restrict__ P2,
    const _Float16* __restrict__ XA,
    const float* __restrict__ tc1, const float* __restrict__ tc2,
    const float* __restrict__ usp, const float* __restrict__ vsp,
    _Float16* __restrict__ U2, _Float16* __restrict__ S)
{
    int bid = blockIdx.x;
    int mh = bid >> 9;                  // 0: gate/u, 1: up/v
    int lg = (bid >> 6) & 7;
    int f0 = (bid & 63) * 16;
    int tid = threadIdx.x;
    int w = tid >> 6, lane = tid & 63;
    int n = lane & 15, kc = lane >> 4;

    const _Float16* P  = mh ? P2 : P1;
    const float*    tc = mh ? tc2 : tc1;

    __shared__ __align__(16) _Float16 Wt[2][16 * 584]; // [buf][l*584+f*36+d]
    __shared__ float CN[256];

    // element-unit base pointers (advance +512 per 32-d chunk)
    const _Float16* pP  = P + ((size_t)(f0 + w * 4) * 512 + n) * 16 + kc * 4;
    const _Float16* pXA = XA + (((size_t)(lg * 16 + w * 4) * 64 + kc) * 16 + n) * 8;

    half4 pa[4][2];
    // ---- prologue: issue pa(0); softmax + barrier cover the latency ----
#pragma unroll
    for (int fl = 0; fl < 4; ++fl)
#pragma unroll
        for (int dg = 0; dg < 2; ++dg)
            pa[fl][dg] = *(const half4*)(pP + fl * 8192 + dg * 256);
    const _Float16* qP = pP + 512;

    if (tid < 16) {
        const float* row = tc + (size_t)(lg * 16 + tid) * 16;
        float e[16], m = -1e30f, sum = 0.f;
#pragma unroll
        for (int k = 0; k < 16; ++k) m = fmaxf(m, row[k]);
#pragma unroll
        for (int k = 0; k < 16; ++k) { e[k] = __expf(row[k] - m); sum += e[k]; }
        float r = 1.f / sum;
#pragma unroll
        for (int k = 0; k < 16; ++k) CN[tid * 16 + k] = e[k] * r;
    }
    __syncthreads();

    half4 cf;
#pragma unroll
    for (int j = 0; j < 4; ++j)
        cf[j] = (_Float16)CN[n * 16 + kc * 4 + j];

    f32x4 zf = { 0.f, 0.f, 0.f, 0.f };
    f32x4 aU[4];
#pragma unroll
    for (int i = 0; i < 4; ++i) aU[i] = zf;
    float nsq[4] = { 0.f, 0.f, 0.f, 0.f };
    half8 xf[4];

#pragma unroll 1
    for (int it = 0; it < 16; ++it) {
        _Float16* WtW = &Wt[it & 1][0];
        const _Float16* WtR = &Wt[(it & 1) ^ 1][0];

        // ---- mix(it) (pa drained at previous barrier), K=16 MFMA ----
#pragma unroll
        for (int fl = 0; fl < 4; ++fl) {
            int f_l = w * 4 + fl;
#pragma unroll
            for (int dg = 0; dg < 2; ++dg) {
                f32x4 c1 = MFMA16(pa[fl][dg], cf, zf, 0, 0, 0);
                nsq[fl] += c1[0] * c1[0] + c1[1] * c1[1]
                         + c1[2] * c1[2] + c1[3] * c1[3];
                half4 h1 = { (_Float16)c1[0], (_Float16)c1[1],
                             (_Float16)c1[2], (_Float16)c1[3] };
                *(half4*)(&WtW[n * 584 + f_l * 36 + dg * 16 + kc * 4]) = h1;
            }
        }
        // ---- issue pa(it+1) into freed regs ----
        if (it < 15) {
#pragma unroll
            for (int fl = 0; fl < 4; ++fl)
#pragma unroll
                for (int dg = 0; dg < 2; ++dg)
                    pa[fl][dg] = *(const half4*)(qP + fl * 8192 + dg * 256);
        }
        // ---- consume(it-1) from the other buffer ----
        if (it > 0) {
#pragma unroll
            for (int li = 0; li < 4; ++li) {
                int l = w * 4 + li;
                half8 wU = *(const half8*)(&WtR[l * 584 + n * 36 + kc * 8]);
                aU[li] = MFMA_F16(xf[li], wU, aU[li], 0, 0, 0);
            }
        }
        // ---- load xf(it): 1KB dense per wave ----
#pragma unroll
        for (int li = 0; li < 4; ++li)
            xf[li] = *(const half8*)(pXA + li * 8192);
        pXA += 512;
        qP += 512;
        __syncthreads();
    }
    // ---- tail consume (chunk 15, buffer 1) ----
#pragma unroll
    for (int li = 0; li < 4; ++li) {
        int l = w * 4 + li;
        half8 wU = *(const half8*)(&Wt[1][l * 584 + n * 36 + kc * 8]);
        aU[li] = MFMA_F16(xf[li], wU, aU[li], 0, 0, 0);
    }

    // ---- norm reduce ----
#pragma unroll
    for (int fl = 0; fl < 4; ++fl) {
        float vU = nsq[fl];
        vU += __shfl_xor(vU, 16); vU += __shfl_xor(vU, 32);
        if (kc == 0) CN[n * 16 + w * 4 + fl] = vU;
    }
    __syncthreads();

    int f = f0 + n;
    float sc = mh ? (fabsf(vsp[f]) * 22.627416997969522f)   // vs = |vsp|*sqrt(512)
                  : fabsf(usp[f]);                          // us = |usp|
    _Float16* Out = mh ? S : U2;
#pragma unroll
    for (int li = 0; li < 4; ++li) {
        int lgl = lg * 16 + w * 4 + li;
        float r1 = 1.f / fmaxf(sqrtf(CN[(w * 4 + li) * 16 + n]), 1e-12f);
#pragma unroll
        for (int i = 0; i < 4; ++i) {
            float val = aU[li][i] * r1 * sc;       // us*u'  or  vs*v'
            if (mh) val = val / (1.f + __expf(-val));   // silu(vs*v')
            // layout [l][f>>3][b][8]
            Out[(((size_t)lgl * 128 + (f >> 3)) * 16 + kc * 4 + i) * 8 + (f & 7)] =
                (_Float16)val;
        }
    }
}

// ---------------------------------------------------------------------------
// down_fast (R13): 1024 blocks = 4 f-quarters x 8 lg x 32 d-tiles.
// Mix uses 16x16x16 MFMA (full-lane P3/cf3 loads); hf = S*U2 in-register.
// ---------------------------------------------------------------------------
__global__ __launch_bounds__(256, 2) void down_fast(
    const _Float16* __restrict__ P3, const float* __restrict__ tc3,
    const _Float16* __restrict__ S, const _Float16* __restrict__ U2,
    float* __restrict__ Rp, float* __restrict__ Np)
{
    int zh = blockIdx.x >> 8;          // 0..3
    int rem = blockIdx.x & 255;
    int lg = rem >> 5;
    int d0 = (rem & 31) * 16;
    int tid = threadIdx.x;
    int w = tid >> 6, lane = tid & 63;
    int n = lane & 15, kc = lane >> 4;

    __shared__ __align__(16) _Float16 Wt[2][16 * 584];    // [buf][l*584 + d*36 + f]
    __shared__ float CN[256];

    // element-unit base pointers (advance +512 per 32-f chunk)
    const _Float16* pP3 = P3 + ((size_t)(d0 + w * 4) * 1024 + zh * 256 + n) * 16 + kc * 4;
    size_t hoff = (((size_t)(lg * 16 + w * 4) * 128 + zh * 32 + kc) * 16 + n) * 8;
    const _Float16* pS = S + hoff;
    const _Float16* pU = U2 + hoff;

    half4 pa[4][2];
    // ---- prologue: issue pa(0) ----
#pragma unroll
    for (int dl = 0; dl < 4; ++dl)
#pragma unroll
        for (int fg = 0; fg < 2; ++fg)
            pa[dl][fg] = *(const half4*)(pP3 + dl * 16384 + fg * 256);
    const _Float16* qP3 = pP3 + 512;

    if (tid < 16) {
        const float* row = tc3 + (size_t)(lg * 16 + tid) * 16;
        float e[16], m = -1e30f, sum = 0.f;
#pragma unroll
        for (int k = 0; k < 16; ++k) m = fmaxf(m, row[k]);
#pragma unroll
        for (int k = 0; k < 16; ++k) { e[k] = __expf(row[k] - m); sum += e[k]; }
        float r = 1.f / sum;
#pragma unroll
        for (int k = 0; k < 16; ++k) CN[tid * 16 + k] = e[k] * r;
    }
    __syncthreads();

    half4 cf3;
#pragma unroll
    for (int j = 0; j < 4; ++j)
        cf3[j] = (_Float16)CN[n * 16 + kc * 4 + j];

    f32x4 zf = { 0.f, 0.f, 0.f, 0.f };
    f32x4 aO[4];
#pragma unroll
    for (int i = 0; i < 4; ++i) aO[i] = zf;
    float nsqD[4] = { 0.f, 0.f, 0.f, 0.f };
    half8 hf[4];

#pragma unroll 1
    for (int it = 0; it < 8; ++it) {
        _Float16* WtW = &Wt[it & 1][0];
        const _Float16* WtR = &Wt[(it & 1) ^ 1][0];

        // ---- mix(it), K=16 MFMA ----
#pragma unroll
        for (int dl = 0; dl < 4; ++dl) {
            int d_l = w * 4 + dl;
#pragma unroll
            for (int fg = 0; fg < 2; ++fg) {
                f32x4 cw = MFMA16(pa[dl][fg], cf3, zf, 0, 0, 0);
                nsqD[dl] += cw[0] * cw[0] + cw[1] * cw[1]
                          + cw[2] * cw[2] + cw[3] * cw[3];
                half4 h4 = { (_Float16)cw[0], (_Float16)cw[1],
                             (_Float16)cw[2], (_Float16)cw[3] };
                *(half4*)(&WtW[n * 584 + d_l * 36 + fg * 16 + kc * 4]) = h4;
            }
        }
        // ---- issue pa(it+1) ----
        if (it < 7) {
#pragma unroll
            for (int dl = 0; dl < 4; ++dl)
#pragma unroll
                for (int fg = 0; fg < 2; ++fg)
                    pa[dl][fg] = *(const half4*)(qP3 + dl * 16384 + fg * 256);
        }
        // ---- consume(it-1) ----
        if (it > 0) {
#pragma unroll
            for (int li = 0; li < 4; ++li) {
                int l = w * 4 + li;
                half8 wf = *(const half8*)(&WtR[l * 584 + n * 36 + kc * 8]);
                aO[li] = MFMA_F16(hf[li], wf, aO[li], 0, 0, 0);
            }
        }
        // ---- load hf(it) = S * U2 (each 1KB dense per wave) ----
#pragma unroll
        for (int li = 0; li < 4; ++li) {
            half8 s8 = *(const half8*)(pS + li * 16384);
            half8 u8 = *(const half8*)(pU + li * 16384);
            hf[li] = s8 * u8;
        }
        pS += 512;
        pU += 512;
        qP3 += 512;
        __syncthreads();
    }
    // ---- tail consume (chunk 7, buffer 1) ----
#pragma unroll
    for (int li = 0; li < 4; ++li) {
        int l = w * 4 + li;
        half8 wf = *(const half8*)(&Wt[1][l * 584 + n * 36 + kc * 8]);
        aO[li] = MFMA_F16(hf[li], wf, aO[li], 0, 0, 0);
    }

#pragma unroll
    for (int dl = 0; dl < 4; ++dl) {
        float v = nsqD[dl];
        v += __shfl_xor(v, 16); v += __shfl_xor(v, 32);
        if (kc == 0)
            Np[(size_t)zh * 65536 + (size_t)(lg * 16 + n) * 512 + d0 + w * 4 + dl] = v;
    }
#pragma unroll
    for (int li = 0; li < 4; ++li) {
        int lgl = lg * 16 + w * 4 + li;
#pragma unroll
        for (int i = 0; i < 4; ++i)
            Rp[(size_t)zh * 1048576 +
               ((size_t)(kc * 4 + i) * 128 + lgl) * 512 + d0 + n] = aO[li][i];
    }
}

// ---------------------------------------------------------------------------
__global__ __launch_bounds__(128) void final_combine(
    const float* __restrict__ Rp, const float* __restrict__ Np,
    float* __restrict__ out)
{
    int rid = blockIdx.x;              // b*128 + l
    int l = rid & 127;
    int t = threadIdx.x;
    f32x4 r = { 0.f, 0.f, 0.f, 0.f };
    f32x4 nn = { 0.f, 0.f, 0.f, 0.f };
#pragma unroll
    for (int zh = 0; zh < 4; ++zh) {
        f32x4 rz = *(const f32x4*)(Rp + (size_t)zh * 1048576 + (size_t)rid * 512 + t * 4);
        f32x4 nz = *(const f32x4*)(Np + (size_t)zh * 65536 + (size_t)l * 512 + t * 4);
#pragma unroll
        for (int j = 0; j < 4; ++j) { r[j] += rz[j]; nn[j] += nz[j]; }
    }
    f32x4 y;
#pragma unroll
    for (int j = 0; j < 4; ++j) {
        float rr = 1.f / fmaxf(sqrtf(fmaxf(nn[j], 0.f)), 1e-12f);
        y[j] = r[j] * rr;
    }
    float s = y[0] * y[0] + y[1] * y[1] + y[2] * y[2] + y[3] * y[3];
#pragma unroll
    for (int off = 32; off > 0; off >>= 1) s += __shfl_down(s, off);
    __shared__ float sred[2];
    if ((t & 63) == 0) sred[t >> 6] = s;
    __syncthreads();
    float rr = 1.f / fmaxf(sqrtf(sred[0] + sred[1]), 1e-12f);
    f32x4 o = { y[0] * rr, y[1] * rr, y[2] * rr, y[3] * rr };
    *(f32x4*)(out + (size_t)rid * 512 + t * 4) = o;
}

// ===========================================================================
// SLOW FALLBACK (round-2 kernels, proven) — used when ws_size < WS_FAST
// ===========================================================================
__global__ __launch_bounds__(256) void up_kernel(
    const float* __restrict__ x,
    const float* __restrict__ wg, const float* __restrict__ wu,
    const float* __restrict__ tc1, const float* __restrict__ tc2,
    const float* __restrict__ usp, const float* __restrict__ vsp,
    _Float16* __restrict__ Hp)
{
    int lg = blockIdx.x >> 6;
    int f0 = (blockIdx.x & 63) * 16;
    int tid = threadIdx.x;
    int w = tid >> 6, lane = tid & 63;
    int n = lane & 15, kc = lane >> 4;

    __shared__ __align__(16) _Float16 Xt[256 * 40];
    __shared__ __align__(16) _Float16 Bh[32 * 16 * 24];
    __shared__ __align__(16) _Float16 Wt[16 * 528];
    __shared__ float CN[2 * 16 * 16];

    if (tid < 32) {
        int s = tid >> 4, ll = tid & 15;
        const float* row = (s ? tc2 : tc1) + (size_t)(lg * 16 + ll) * 16;
        float e[16], m = -1e30f, sum = 0.f;
#pragma unroll
        for (int k = 0; k < 16; ++k) m = fmaxf(m, row[k]);
#pragma unroll
        for (int k = 0; k < 16; ++k) { e[k] = __expf(row[k] - m); sum += e[k]; }
        float r = 1.f / sum;
#pragma unroll
        for (int k = 0; k < 16; ++k) CN[s * 256 + ll * 16 + k] = e[k] * r;
    }
    __syncthreads();

    half8 cf1 = { 0, 0, 0, 0, 0, 0, 0, 0 };
    half8 cf2 = { 0, 0, 0, 0, 0, 0, 0, 0 };
    if (kc < 2) {
#pragma unroll
        for (int j = 0; j < 8; ++j) {
            cf1[j] = (_Float16)CN[0 * 256 + n * 16 + kc * 8 + j];
            cf2[j] = (_Float16)CN[1 * 256 + n * 16 + kc * 8 + j];
        }
    }

    f32x4 zf = { 0.f, 0.f, 0.f, 0.f };
    f32x4 aU[4], aV[4];
#pragma unroll
    for (int i = 0; i < 4; ++i) { aU[i] = zf; aV[i] = zf; }
    float nsqU[4] = { 0.f, 0.f, 0.f, 0.f };
    float nsqV[4] = { 0.f, 0.f, 0.f, 0.f };

    for (int it = 0; it < 16; ++it) {
        int d0 = it * 32;
#pragma unroll
        for (int p = 0; p < 8; ++p) {
            int r = p * 32 + (tid >> 3);
            int fj = tid & 7;
            int ll = r >> 4, b = r & 15;
            f32x4 v = *(const f32x4*)(
                x + ((size_t)(b * 128 + lg * 16 + ll) * 512 + d0 + fj * 4));
            half4 h = { (_Float16)v[0], (_Float16)v[1],
                        (_Float16)v[2], (_Float16)v[3] };
            *(half4*)(&Xt[r * 40 + fj * 4]) = h;
        }
#pragma unroll
        for (int p = 0; p < 8; ++p) {
            int idx = p * 256 + tid;
            int q = idx & 3, dd = (idx >> 2) & 31, k = idx >> 7;
            f32x4 v = *(const f32x4*)(
                wg + ((size_t)k * 512 + d0 + dd) * 1024 + f0 + q * 4);
#pragma unroll
            for (int j = 0; j < 4; ++j)
                Bh[(dd * 16 + q * 4 + j) * 24 + k] = (_Float16)v[j];
        }
        __syncthreads();
#pragma unroll
        for (int fl = 0; fl < 4; ++fl) {
            int f_l = w * 4 + fl;
#pragma unroll
            for (int dg = 0; dg < 2; ++dg) {
                half8 a = { 0, 0, 0, 0, 0, 0, 0, 0 };
                if (kc < 2)
                    a = *(const half8*)(&Bh[((dg * 16 + n) * 16 + f_l) * 24 + kc * 8]);
                f32x4 cw = MFMA_F16(a, cf1, zf, 0, 0, 0);
                nsqU[fl] += cw[0] * cw[0] + cw[1] * cw[1]
                          + cw[2] * cw[2] + cw[3] * cw[3];
                half4 h4 = { (_Float16)cw[0], (_Float16)cw[1],
                             (_Float16)cw[2], (_Float16)cw[3] };
                *(half4*)(&Wt[n * 528 + f_l * 32 + dg * 16 + kc * 4]) = h4;
            }
        }
        __syncthreads();
#pragma unroll
        for (int li = 0; li < 4; ++li) {
            int l = w * 4 + li;
            half8 xf = *(const half8*)(&Xt[(l * 16 + n) * 40 + kc * 8]);
            half8 wf = *(const half8*)(&Wt[l * 528 + n * 32 + kc * 8]);
            aU[li] = MFMA_F16(xf, wf, aU[li], 0, 0, 0);
        }
#pragma unroll
        for (int p = 0; p < 8; ++p) {
            int idx = p * 256 + tid;
            int q = idx & 3, dd = (idx >> 2) & 31, k = idx >> 7;
            f32x4 v = *(const f32x4*)(
                wu + ((size_t)k * 512 + d0 + dd) * 1024 + f0 + q * 4);
#pragma unroll
            for (int j = 0; j < 4; ++j)
                Bh[(dd * 16 + q * 4 + j) * 24 + k] = (_Float16)v[j];
        }
        __syncthreads();
#pragma unroll
        for (int fl = 0; fl < 4; ++fl) {
            int f_l = w * 4 + fl;
#pragma unroll
            for (int dg = 0; dg < 2; ++dg) {
                half8 a = { 0, 0, 0, 0, 0, 0, 0, 0 };
                if (kc < 2)
                    a = *(const half8*)(&Bh[((dg * 16 + n) * 16 + f_l) * 24 + kc * 8]);
                f32x4 cw = MFMA_F16(a, cf2, zf, 0, 0, 0);
                nsqV[fl] += cw[0] * cw[0] + cw[1] * cw[1]
                          + cw[2] * cw[2] + cw[3] * cw[3];
                half4 h4 = { (_Float16)cw[0], (_Float16)cw[1],
                             (_Float16)cw[2], (_Float16)cw[3] };
                *(half4*)(&Wt[n * 528 + f_l * 32 + dg * 16 + kc * 4]) = h4;
            }
        }
        __syncthreads();
#pragma unroll
        for (int li = 0; li < 4; ++li) {
            int l = w * 4 + li;
            half8 xf = *(const half8*)(&Xt[(l * 16 + n) * 40 + kc * 8]);
            half8 wf = *(const half8*)(&Wt[l * 528 + n * 32 + kc * 8]);
            aV[li] = MFMA_F16(xf, wf, aV[li], 0, 0, 0);
        }
        __syncthreads();
    }

#pragma unroll
    for (int fl = 0; fl < 4; ++fl) {
        float vU = nsqU[fl], vV = nsqV[fl];
        vU += __shfl_xor(vU, 16); vU += __shfl_xor(vU, 32);
        vV += __shfl_xor(vV, 16); vV += __shfl_xor(vV, 32);
        if (kc == 0) {
            CN[0 * 256 + n * 16 + w * 4 + fl] = vU;
            CN[1 * 256 + n * 16 + w * 4 + fl] = vV;
        }
    }
    __syncthreads();

    int f = f0 + n;
    float usv = fabsf(usp[f]);
    float vsv = fabsf(vsp[f]) * 22.627416997969522f;
#pragma unroll
    for (int li = 0; li < 4; ++li) {
        int lgl = lg * 16 + w * 4 + li;
        float r1 = 1.f / fmaxf(sqrtf(CN[0 * 256 + (w * 4 + li) * 16 + n]), 1e-12f);
        float r2 = 1.f / fmaxf(sqrtf(CN[1 * 256 + (w * 4 + li) * 16 + n]), 1e-12f);
#pragma unroll
        for (int i = 0; i < 4; ++i) {
            float u = aU[li][i] * r1;
            float v = aV[li][i] * r2;
            float zz = vsv * v;
            float sil = zz / (1.f + __expf(-zz));
            float h = sil * (usv * u);
            Hp[((size_t)lgl * 16 + kc * 4 + i) * 1024 + f] = (_Float16)h;
        }
    }
}

__global__ __launch_bounds__(256) void down_kernel(
    const float* __restrict__ wd, const float* __restrict__ tc3,
    const _Float16* __restrict__ Hp, float* __restrict__ out)
{
    int lg = blockIdx.x >> 5;
    int d0 = (blockIdx.x & 31) * 16;
    int tid = threadIdx.x;
    int w = tid >> 6, lane = tid & 63;
    int n = lane & 15, kc = lane >> 4;

    __shared__ __align__(16) _Float16 Ht[256 * 40];
    __shared__ __align__(16) _Float16 Bh[32 * 16 * 24];
    __shared__ __align__(16) _Float16 Wt[16 * 528];
    __shared__ float CN[16 * 16];

    if (tid < 16) {
        const float* row = tc3 + (size_t)(lg * 16 + tid) * 16;
        float e[16], m = -1e30f, sum = 0.f;
#pragma unroll
        for (int k = 0; k < 16; ++k) m = fmaxf(m, row[k]);
#pragma unroll
        for (int k = 0; k < 16; ++k) { e[k] = __expf(row[k] - m); sum += e[k]; }
        float r = 1.f / sum;
#pragma unroll
        for (int k = 0; k < 16; ++k) CN[tid * 16 + k] = e[k] * r;
    }
    __syncthreads();

    half8 cf3 = { 0, 0, 0, 0, 0, 0, 0, 0 };
    if (kc < 2) {
#pragma unroll
        for (int j = 0; j < 8; ++j)
            cf3[j] = (_Float16)CN[n * 16 + kc * 8 + j];
    }

    f32x4 zf = { 0.f, 0.f, 0.f, 0.f };
    f32x4 aO[4];
#pragma unroll
    for (int i = 0; i < 4; ++i) aO[i] = zf;
    float nsqD[4] = { 0.f, 0.f, 0.f, 0.f };

    for (int it = 0; it < 32; ++it) {
        int f0 = it * 32;
#pragma unroll
        for (int p = 0; p < 8; ++p) {
            int r = p * 32 + (tid >> 3);
            int hj = tid & 7;
            int ll = r >> 4, b = r & 15;
            half4 v = *(const half4*)(
                Hp + ((size_t)(lg * 16 + ll) * 16 + b) * 1024 + f0 + hj * 4);
            *(half4*)(&Ht[r * 40 + hj * 4]) = v;
        }
#pragma unroll
        for (int p = 0; p < 8; ++p) {
            int idx = p * 256 + tid;
            int q = idx & 3, ff = (idx >> 2) & 31, k = idx >> 7;
            f32x4 v = *(const f32x4*)(
                wd + ((size_t)k * 1024 + f0 + ff) * 512 + d0 + q * 4);
#pragma unroll
            for (int j = 0; j < 4; ++j)
                Bh[(ff * 16 + q * 4 + j) * 24 + k] = (_Float16)v[j];
        }
        __syncthreads();
#pragma unroll
        for (int dl = 0; dl < 4; ++dl) {
            int d_l = w * 4 + dl;
#pragma unroll
            for (int fg = 0; fg < 2; ++fg) {
                half8 a = { 0, 0, 0, 0, 0, 0, 0, 0 };
                if (kc < 2)
                    a = *(const half8*)(&Bh[((fg * 16 + n) * 16 + d_l) * 24 + kc * 8]);
                f32x4 cw = MFMA_F16(a, cf3, zf, 0, 0, 0);
                nsqD[dl] += cw[0] * cw[0] + cw[1] * cw[1]
                          + cw[2] * cw[2] + cw[3] * cw[3];
                half4 h4 = { (_Float16)cw[0], (_Float16)cw[1],
                             (_Float16)cw[2], (_Float16)cw[3] };
                *(half4*)(&Wt[n * 528 + d_l * 32 + fg * 16 + kc * 4]) = h4;
            }
        }
        __syncthreads();
#pragma unroll
        for (int li = 0; li < 4; ++li) {
            int l = w * 4 + li;
            half8 hf = *(const half8*)(&Ht[(l * 16 + n) * 40 + kc * 8]);
            half8 wf = *(const half8*)(&Wt[l * 528 + n * 32 + kc * 8]);
            aO[li] = MFMA_F16(hf, wf, aO[li], 0, 0, 0);
        }
        __syncthreads();
    }

#pragma unroll
    for (int dl = 0; dl < 4; ++dl) {
        float v = nsqD[dl];
        v += __shfl_xor(v, 16); v += __shfl_xor(v, 32);
        if (kc == 0) CN[n * 16 + w * 4 + dl] = v;
    }
    __syncthreads();

#pragma unroll
    for (int li = 0; li < 4; ++li) {
        int lgl = lg * 16 + w * 4 + li;
        float r3 = 1.f / fmaxf(sqrtf(CN[(w * 4 + li) * 16 + n]), 1e-12f);
#pragma unroll
        for (int i = 0; i < 4; ++i)
            out[((size_t)(kc * 4 + i) * 128 + lgl) * 512 + d0 + n] = aO[li][i] * r3;
    }
}

__global__ __launch_bounds__(128) void final_kernel(float* __restrict__ out)
{
    int rid = blockIdx.x;
    int t = threadIdx.x;
    f32x4 y = *(const f32x4*)(out + (size_t)rid * 512 + t * 4);
    float s = y[0] * y[0] + y[1] * y[1] + y[2] * y[2] + y[3] * y[3];
#pragma unroll
    for (int off = 32; off > 0; off >>= 1) s += __shfl_down(s, off);
    __shared__ float sred[2];
    if ((t & 63) == 0) sred[t >> 6] = s;
    __syncthreads();
    float rr = 1.f / fmaxf(sqrtf(sred[0] + sred[1]), 1e-12f);
    f32x4 o = { y[0] * rr, y[1] * rr, y[2] * rr, y[3] * rr };
    *(f32x4*)(out + (size_t)rid * 512 + t * 4) = o;
}

// ---------------------------------------------------------------------------
extern "C" void kernel_launch(void* const* d_in, const int* in_sizes, int n_in,
                              void* d_out, int out_size, void* d_ws, size_t ws_size,
                              hipStream_t stream)
{
    (void)in_sizes; (void)n_in; (void)out_size;
    const float* x   = (const float*)d_in[0];
    const float* wg  = (const float*)d_in[1];
    const float* wu  = (const float*)d_in[2];
    const float* wd  = (const float*)d_in[3];
    const float* tc1 = (const float*)d_in[4];
    const float* tc2 = (const float*)d_in[5];
    const float* tc3 = (const float*)d_in[6];
    const float* usp = (const float*)d_in[7];
    const float* vsp = (const float*)d_in[8];
    float* outp = (float*)d_out;
    char* ws = (char*)d_ws;

    if (ws_size >= WS_FAST) {
        _Float16* P1  = (_Float16*)(ws + OFF_P1);
        _Float16* P2  = (_Float16*)(ws + OFF_P2);
        _Float16* P3n = (_Float16*)(ws + OFF_P3n);  // 17..33 MiB (after Np)
        _Float16* XA  = (_Float16*)(ws + OFF_XA);   // 32..34 MiB
        _Float16* U2  = (_Float16*)(ws + OFF_U2);   // 34..38 MiB
        _Float16* S   = (_Float16*)(ws + OFF_S);    // 38..42 MiB
        float* Rp = (float*)(ws + OFF_P1);   // overlays P1 (dead after up)
        float* Np = (float*)(ws + OFF_P2);   // 16..17 MiB (P2 dead after up)
        prep_basis_all<<<dim3(512, 2), dim3(256), 0, stream>>>(
            wg, wu, wd, P1, P2, P3n, 0);                   // P1, P2
        prep_x<<<dim3(256), dim3(256), 0, stream>>>(x, XA);
        up_split<<<dim3(1024), dim3(256), 0, stream>>>(P1, P2, XA, tc1, tc2,
                                                       usp, vsp, U2, S);
        prep_basis_all<<<dim3(512, 1), dim3(256), 0, stream>>>(
            wg, wu, wd, P1, P2, P3n, 2);                   // P3 at 17 MiB
        down_fast<<<dim3(1024), dim3(256), 0, stream>>>(P3n, tc3, S, U2, Rp, Np);
        final_combine<<<dim3(2048), dim3(128), 0, stream>>>(Rp, Np, outp);
    } else {
        _Float16* Hp = (_Float16*)ws;
        up_kernel<<<dim3(512), dim3(256), 0, stream>>>(x, wg, wu, tc1, tc2,
                                                       usp, vsp, Hp);
        down_kernel<<<dim3(256), dim3(256), 0, stream>>>(wd, tc3, Hp, outp);
        final_kernel<<<dim3(2048), dim3(128), 0, stream>>>(outp);
    }
}

// Round 7
// 225.046 us; speedup vs baseline: 1.1154x; 1.0051x over previous
//
#include <hip/hip_runtime.h>
#include <hip/hip_bf16.h>
#include <cmath>

// ---------------------------------------------------------------------------
// NPerTokenSwishGLU_Basis — fused f16-MFMA implementation (gfx950), round 14.
//
// R13 post-mortem: 226us (win). up_split still latency-shaped (VALU 25%,
// Mfma 9.6%, HBM 9%) at 4 blocks/CU -> the per-iteration __syncthreads'
// full vmcnt(0) drain discards our prefetch overlap every iteration.
// R14: replace in-loop __syncthreads with {s_waitcnt lgkmcnt(0); s_barrier}
// (T4 counted-wait pattern). Only LDS crosses the barrier: lgkmcnt(0)
// drains ds_writes (visibility) and ds_reads (WAR) — global prefetches into
// private VGPRs stay in flight across the barrier; the compiler inserts its
// own vmcnt waits before their uses. down_fast also gets
// __launch_bounds__(256,4) (LDS 38.4KB already admits 4 blocks/CU).
// ---------------------------------------------------------------------------

typedef _Float16 half8 __attribute__((ext_vector_type(8)));
typedef _Float16 half4 __attribute__((ext_vector_type(4)));
typedef float    f32x4 __attribute__((ext_vector_type(4)));
typedef float    f32x2 __attribute__((ext_vector_type(2)));

#define MFMA_F16  __builtin_amdgcn_mfma_f32_16x16x32_f16
#define MFMA16    __builtin_amdgcn_mfma_f32_16x16x16f16

// LDS-only barrier: drain DS ops, leave global loads in flight (T4).
#define LDS_BARRIER()                                           \
    do {                                                        \
        asm volatile("s_waitcnt lgkmcnt(0)" ::: "memory");      \
        __builtin_amdgcn_s_barrier();                           \
    } while (0)

static constexpr size_t OFF_P1  = 0;            // 16 MiB; Rp overlay (down)
static constexpr size_t OFF_P2  = 16777216;     // 16 MiB; Np overlay (down, 1 MiB)
static constexpr size_t OFF_P3n = 17825792;     // 16 MiB at 17 MiB (after Np)
static constexpr size_t OFF_XA  = 33554432;     // 2 MiB at 32 MiB
static constexpr size_t OFF_U2  = 35651584;     // 4 MiB at 34 MiB
static constexpr size_t OFF_S   = 39845888;     // 4 MiB at 38 MiB (top 42 MiB)
static constexpr size_t WS_FAST = 54525952;     // 52 MiB (proven)

// ---------------------------------------------------------------------------
// prep (two-sided coalesced transpose), 32x32 tiles (R13):
//   z=0,1: wg/wu (K,512,1024)=[k][d][f] -> P[f][d][k]
//   z=2  : wd    (K,1024,512)=[k][f][d] -> P3[d][f][k]
// ---------------------------------------------------------------------------
__global__ __launch_bounds__(256) void prep_basis_all(
    const float* __restrict__ wg, const float* __restrict__ wu,
    const float* __restrict__ wd,
    _Float16* __restrict__ P1, _Float16* __restrict__ P2,
    _Float16* __restrict__ P3, int zoff)
{
    int z = blockIdx.y + zoff;
    const float* src = (z == 0) ? wg : (z == 1) ? wu : wd;
    _Float16*    dst = (z == 0) ? P1 : (z == 1) ? P2 : P3;
    int Amin = (z == 2) ? 1024 : 512;    // minor-dim size
    int Bmaj = (z == 2) ? 512 : 1024;    // major-dim size
    int nM = Bmaj >> 5;
    int m0 = (blockIdx.x / nM) * 32;     // minor base
    int M0 = (blockIdx.x % nM) * 32;     // major base

    __shared__ float S[16 * 1088];       // [k][row*34 + col]
    int t = threadIdx.x;

    int row = t >> 3;                    // 0..31 (minor row)
    int cg  = t & 7;                     // 0..7 (16B col group)
#pragma unroll
    for (int k = 0; k < 16; ++k) {
        f32x4 v = *(const f32x4*)(
            src + (size_t)k * Amin * Bmaj + (size_t)(m0 + row) * Bmaj + M0 + cg * 4);
        f32x2 lo = { v[0], v[1] };
        f32x2 hi = { v[2], v[3] };
        *(f32x2*)(&S[k * 1088 + row * 34 + cg * 4])     = lo;
        *(f32x2*)(&S[k * 1088 + row * 34 + cg * 4 + 2]) = hi;
    }
    __syncthreads();

    int mn = t & 31, mjq = t >> 5;
#pragma unroll
    for (int q = 0; q < 4; ++q) {
        int mj = q * 8 + mjq;
        half8 v0, v1;
#pragma unroll
        for (int k = 0; k < 8; ++k) v0[k] = (_Float16)S[k * 1088 + mn * 34 + mj];
#pragma unroll
        for (int k = 0; k < 8; ++k) v1[k] = (_Float16)S[(k + 8) * 1088 + mn * 34 + mj];
        _Float16* out = dst + ((size_t)(M0 + mj) * Amin + m0 + mn) * 16;
        *(half8*)out       = v0;
        *(half8*)(out + 8) = v1;
    }
}

// ---------------------------------------------------------------------------
// prep_x: x fp32 [b][l][d] -> XA f16 [l][d>>3][b][8]
// grid 256 = 128 l x 2 b-halves, 256 threads.
// ---------------------------------------------------------------------------
__global__ __launch_bounds__(256) void prep_x(
    const float* __restrict__ x, _Float16* __restrict__ XA)
{
    int l = blockIdx.x >> 1, bh = blockIdx.x & 1;
    __shared__ __align__(16) _Float16 XT[8][524];
    int t = threadIdx.x;

    int bl = t >> 5, q = t & 31;          // b-local 0..7, q 0..31
    int b = bh * 8 + bl;
#pragma unroll
    for (int j = 0; j < 4; ++j) {
        f32x4 v = *(const f32x4*)(x + ((size_t)(b * 128 + l) * 512 + j * 128 + q * 4));
#pragma unroll
        for (int i = 0; i < 4; ++i)
            XT[bl][j * 128 + q * 4 + i] = (_Float16)v[i];
    }
    __syncthreads();

    int c = t >> 2, bi = t & 3;           // c 0..63
#pragma unroll
    for (int s = 0; s < 2; ++s) {
        int blw = bi * 2 + s;             // 0..7
        half8 h = *(const half8*)(&XT[blw][c * 8]);
        *(half8*)(XA + (((size_t)(l * 64 + c) * 16 + bh * 8 + blw) * 8)) = h;
    }
}

// ---------------------------------------------------------------------------
// up_split (R14): 1024 blocks = mh(2) x 8 lg x 64 f-tiles, 256 thr / 4 waves.
// Mix uses 16x16x16 MFMA; in-loop barrier is LDS_BARRIER (global loads stay
// in flight). LDS: Wt[2][16*584] + CN -> 4 blocks/CU.
// ---------------------------------------------------------------------------
__global__ __launch_bounds__(256, 4) void up_split(
    const _Float16* __restrict__ P1, const _Float16* __restrict__ P2,
    const _Float16* __restrict__ XA,
    const float* __restrict__ tc1, const float* __restrict__ tc2,
    const float* __restrict__ usp, const float* __restrict__ vsp,
    _Float16* __restrict__ U2, _Float16* __restrict__ S)
{
    int bid = blockIdx.x;
    int mh = bid >> 9;                  // 0: gate/u, 1: up/v
    int lg = (bid >> 6) & 7;
    int f0 = (bid & 63) * 16;
    int tid = threadIdx.x;
    int w = tid >> 6, lane = tid & 63;
    int n = lane & 15, kc = lane >> 4;

    const _Float16* P  = mh ? P2 : P1;
    const float*    tc = mh ? tc2 : tc1;

    __shared__ __align__(16) _Float16 Wt[2][16 * 584]; // [buf][l*584+f*36+d]
    __shared__ float CN[256];

    // element-unit base pointers (advance +512 per 32-d chunk)
    const _Float16* pP  = P + ((size_t)(f0 + w * 4) * 512 + n) * 16 + kc * 4;
    const _Float16* pXA = XA + (((size_t)(lg * 16 + w * 4) * 64 + kc) * 16 + n) * 8;

    half4 pa[4][2];
    // ---- prologue: issue pa(0); softmax + barrier cover the latency ----
#pragma unroll
    for (int fl = 0; fl < 4; ++fl)
#pragma unroll
        for (int dg = 0; dg < 2; ++dg)
            pa[fl][dg] = *(const half4*)(pP + fl * 8192 + dg * 256);
    const _Float16* qP = pP + 512;

    if (tid < 16) {
        const float* row = tc + (size_t)(lg * 16 + tid) * 16;
        float e[16], m = -1e30f, sum = 0.f;
#pragma unroll
        for (int k = 0; k < 16; ++k) m = fmaxf(m, row[k]);
#pragma unroll
        for (int k = 0; k < 16; ++k) { e[k] = __expf(row[k] - m); sum += e[k]; }
        float r = 1.f / sum;
#pragma unroll
        for (int k = 0; k < 16; ++k) CN[tid * 16 + k] = e[k] * r;
    }
    __syncthreads();

    half4 cf;
#pragma unroll
    for (int j = 0; j < 4; ++j)
        cf[j] = (_Float16)CN[n * 16 + kc * 4 + j];

    f32x4 zf = { 0.f, 0.f, 0.f, 0.f };
    f32x4 aU[4];
#pragma unroll
    for (int i = 0; i < 4; ++i) aU[i] = zf;
    float nsq[4] = { 0.f, 0.f, 0.f, 0.f };
    half8 xf[4];

#pragma unroll 1
    for (int it = 0; it < 16; ++it) {
        _Float16* WtW = &Wt[it & 1][0];
        const _Float16* WtR = &Wt[(it & 1) ^ 1][0];

        // ---- mix(it) (pa in flight; compiler waits vmcnt), K=16 MFMA ----
#pragma unroll
        for (int fl = 0; fl < 4; ++fl) {
            int f_l = w * 4 + fl;
#pragma unroll
            for (int dg = 0; dg < 2; ++dg) {
                f32x4 c1 = MFMA16(pa[fl][dg], cf, zf, 0, 0, 0);
                nsq[fl] += c1[0] * c1[0] + c1[1] * c1[1]
                         + c1[2] * c1[2] + c1[3] * c1[3];
                half4 h1 = { (_Float16)c1[0], (_Float16)c1[1],
                             (_Float16)c1[2], (_Float16)c1[3] };
                *(half4*)(&WtW[n * 584 + f_l * 36 + dg * 16 + kc * 4]) = h1;
            }
        }
        // ---- issue pa(it+1) into freed regs ----
        if (it < 15) {
#pragma unroll
            for (int fl = 0; fl < 4; ++fl)
#pragma unroll
                for (int dg = 0; dg < 2; ++dg)
                    pa[fl][dg] = *(const half4*)(qP + fl * 8192 + dg * 256);
        }
        // ---- consume(it-1) from the other buffer ----
        if (it > 0) {
#pragma unroll
            for (int li = 0; li < 4; ++li) {
                int l = w * 4 + li;
                half8 wU = *(const half8*)(&WtR[l * 584 + n * 36 + kc * 8]);
                aU[li] = MFMA_F16(xf[li], wU, aU[li], 0, 0, 0);
            }
        }
        // ---- load xf(it): 1KB dense per wave ----
#pragma unroll
        for (int li = 0; li < 4; ++li)
            xf[li] = *(const half8*)(pXA + li * 8192);
        pXA += 512;
        qP += 512;
        LDS_BARRIER();   // drain DS only; global prefetches stay in flight
    }
    // ---- tail consume (chunk 15, buffer 1) ----
#pragma unroll
    for (int li = 0; li < 4; ++li) {
        int l = w * 4 + li;
        half8 wU = *(const half8*)(&Wt[1][l * 584 + n * 36 + kc * 8]);
        aU[li] = MFMA_F16(xf[li], wU, aU[li], 0, 0, 0);
    }

    // ---- norm reduce ----
#pragma unroll
    for (int fl = 0; fl < 4; ++fl) {
        float vU = nsq[fl];
        vU += __shfl_xor(vU, 16); vU += __shfl_xor(vU, 32);
        if (kc == 0) CN[n * 16 + w * 4 + fl] = vU;
    }
    __syncthreads();

    int f = f0 + n;
    float sc = mh ? (fabsf(vsp[f]) * 22.627416997969522f)   // vs = |vsp|*sqrt(512)
                  : fabsf(usp[f]);                          // us = |usp|
    _Float16* Out = mh ? S : U2;
#pragma unroll
    for (int li = 0; li < 4; ++li) {
        int lgl = lg * 16 + w * 4 + li;
        float r1 = 1.f / fmaxf(sqrtf(CN[(w * 4 + li) * 16 + n]), 1e-12f);
#pragma unroll
        for (int i = 0; i < 4; ++i) {
            float val = aU[li][i] * r1 * sc;       // us*u'  or  vs*v'
            if (mh) val = val / (1.f + __expf(-val));   // silu(vs*v')
            // layout [l][f>>3][b][8]
            Out[(((size_t)lgl * 128 + (f >> 3)) * 16 + kc * 4 + i) * 8 + (f & 7)] =
                (_Float16)val;
        }
    }
}

// ---------------------------------------------------------------------------
// down_fast (R14): 1024 blocks = 4 f-quarters x 8 lg x 32 d-tiles.
// LDS_BARRIER in-loop; __launch_bounds__(256,4) targets 4 blocks/CU.
// ---------------------------------------------------------------------------
__global__ __launch_bounds__(256, 4) void down_fast(
    const _Float16* __restrict__ P3, const float* __restrict__ tc3,
    const _Float16* __restrict__ S, const _Float16* __restrict__ U2,
    float* __restrict__ Rp, float* __restrict__ Np)
{
    int zh = blockIdx.x >> 8;          // 0..3
    int rem = blockIdx.x & 255;
    int lg = rem >> 5;
    int d0 = (rem & 31) * 16;
    int tid = threadIdx.x;
    int w = tid >> 6, lane = tid & 63;
    int n = lane & 15, kc = lane >> 4;

    __shared__ __align__(16) _Float16 Wt[2][16 * 584];    // [buf][l*584 + d*36 + f]
    __shared__ float CN[256];

    // element-unit base pointers (advance +512 per 32-f chunk)
    const _Float16* pP3 = P3 + ((size_t)(d0 + w * 4) * 1024 + zh * 256 + n) * 16 + kc * 4;
    size_t hoff = (((size_t)(lg * 16 + w * 4) * 128 + zh * 32 + kc) * 16 + n) * 8;
    const _Float16* pS = S + hoff;
    const _Float16* pU = U2 + hoff;

    half4 pa[4][2];
    // ---- prologue: issue pa(0) ----
#pragma unroll
    for (int dl = 0; dl < 4; ++dl)
#pragma unroll
        for (int fg = 0; fg < 2; ++fg)
            pa[dl][fg] = *(const half4*)(pP3 + dl * 16384 + fg * 256);
    const _Float16* qP3 = pP3 + 512;

    if (tid < 16) {
        const float* row = tc3 + (size_t)(lg * 16 + tid) * 16;
        float e[16], m = -1e30f, sum = 0.f;
#pragma unroll
        for (int k = 0; k < 16; ++k) m = fmaxf(m, row[k]);
#pragma unroll
        for (int k = 0; k < 16; ++k) { e[k] = __expf(row[k] - m); sum += e[k]; }
        float r = 1.f / sum;
#pragma unroll
        for (int k = 0; k < 16; ++k) CN[tid * 16 + k] = e[k] * r;
    }
    __syncthreads();

    half4 cf3;
#pragma unroll
    for (int j = 0; j < 4; ++j)
        cf3[j] = (_Float16)CN[n * 16 + kc * 4 + j];

    f32x4 zf = { 0.f, 0.f, 0.f, 0.f };
    f32x4 aO[4];
#pragma unroll
    for (int i = 0; i < 4; ++i) aO[i] = zf;
    float nsqD[4] = { 0.f, 0.f, 0.f, 0.f };
    half8 hf[4];

#pragma unroll 1
    for (int it = 0; it < 8; ++it) {
        _Float16* WtW = &Wt[it & 1][0];
        const _Float16* WtR = &Wt[(it & 1) ^ 1][0];

        // ---- mix(it), K=16 MFMA ----
#pragma unroll
        for (int dl = 0; dl < 4; ++dl) {
            int d_l = w * 4 + dl;
#pragma unroll
            for (int fg = 0; fg < 2; ++fg) {
                f32x4 cw = MFMA16(pa[dl][fg], cf3, zf, 0, 0, 0);
                nsqD[dl] += cw[0] * cw[0] + cw[1] * cw[1]
                          + cw[2] * cw[2] + cw[3] * cw[3];
                half4 h4 = { (_Float16)cw[0], (_Float16)cw[1],
                             (_Float16)cw[2], (_Float16)cw[3] };
                *(half4*)(&WtW[n * 584 + d_l * 36 + fg * 16 + kc * 4]) = h4;
            }
        }
        // ---- issue pa(it+1) ----
        if (it < 7) {
#pragma unroll
            for (int dl = 0; dl < 4; ++dl)
#pragma unroll
                for (int fg = 0; fg < 2; ++fg)
                    pa[dl][fg] = *(const half4*)(qP3 + dl * 16384 + fg * 256);
        }
        // ---- consume(it-1) ----
        if (it > 0) {
#pragma unroll
            for (int li = 0; li < 4; ++li) {
                int l = w * 4 + li;
                half8 wf = *(const half8*)(&WtR[l * 584 + n * 36 + kc * 8]);
                aO[li] = MFMA_F16(hf[li], wf, aO[li], 0, 0, 0);
            }
        }
        // ---- load hf(it) = S * U2 (each 1KB dense per wave) ----
#pragma unroll
        for (int li = 0; li < 4; ++li) {
            half8 s8 = *(const half8*)(pS + li * 16384);
            half8 u8 = *(const half8*)(pU + li * 16384);
            hf[li] = s8 * u8;
        }
        pS += 512;
        pU += 512;
        qP3 += 512;
        LDS_BARRIER();   // drain DS only; global prefetches stay in flight
    }
    // ---- tail consume (chunk 7, buffer 1) ----
#pragma unroll
    for (int li = 0; li < 4; ++li) {
        int l = w * 4 + li;
        half8 wf = *(const half8*)(&Wt[1][l * 584 + n * 36 + kc * 8]);
        aO[li] = MFMA_F16(hf[li], wf, aO[li], 0, 0, 0);
    }

#pragma unroll
    for (int dl = 0; dl < 4; ++dl) {
        float v = nsqD[dl];
        v += __shfl_xor(v, 16); v += __shfl_xor(v, 32);
        if (kc == 0)
            Np[(size_t)zh * 65536 + (size_t)(lg * 16 + n) * 512 + d0 + w * 4 + dl] = v;
    }
#pragma unroll
    for (int li = 0; li < 4; ++li) {
        int lgl = lg * 16 + w * 4 + li;
#pragma unroll
        for (int i = 0; i < 4; ++i)
            Rp[(size_t)zh * 1048576 +
               ((size_t)(kc * 4 + i) * 128 + lgl) * 512 + d0 + n] = aO[li][i];
    }
}

// ---------------------------------------------------------------------------
__global__ __launch_bounds__(128) void final_combine(
    const float* __restrict__ Rp, const float* __restrict__ Np,
    float* __restrict__ out)
{
    int rid = blockIdx.x;              // b*128 + l
    int l = rid & 127;
    int t = threadIdx.x;
    f32x4 r = { 0.f, 0.f, 0.f, 0.f };
    f32x4 nn = { 0.f, 0.f, 0.f, 0.f };
#pragma unroll
    for (int zh = 0; zh < 4; ++zh) {
        f32x4 rz = *(const f32x4*)(Rp + (size_t)zh * 1048576 + (size_t)rid * 512 + t * 4);
        f32x4 nz = *(const f32x4*)(Np + (size_t)zh * 65536 + (size_t)l * 512 + t * 4);
#pragma unroll
        for (int j = 0; j < 4; ++j) { r[j] += rz[j]; nn[j] += nz[j]; }
    }
    f32x4 y;
#pragma unroll
    for (int j = 0; j < 4; ++j) {
        float rr = 1.f / fmaxf(sqrtf(fmaxf(nn[j], 0.f)), 1e-12f);
        y[j] = r[j] * rr;
    }
    float s = y[0] * y[0] + y[1] * y[1] + y[2] * y[2] + y[3] * y[3];
#pragma unroll
    for (int off = 32; off > 0; off >>= 1) s += __shfl_down(s, off);
    __shared__ float sred[2];
    if ((t & 63) == 0) sred[t >> 6] = s;
    __syncthreads();
    float rr = 1.f / fmaxf(sqrtf(sred[0] + sred[1]), 1e-12f);
    f32x4 o = { y[0] * rr, y[1] * rr, y[2] * rr, y[3] * rr };
    *(f32x4*)(out + (size_t)rid * 512 + t * 4) = o;
}

// ===========================================================================
// SLOW FALLBACK (round-2 kernels, proven) — used when ws_size < WS_FAST
// ===========================================================================
__global__ __launch_bounds__(256) void up_kernel(
    const float* __restrict__ x,
    const float* __restrict__ wg, const float* __restrict__ wu,
    const float* __restrict__ tc1, const float* __restrict__ tc2,
    const float* __restrict__ usp, const float* __restrict__ vsp,
    _Float16* __restrict__ Hp)
{
    int lg = blockIdx.x >> 6;
    int f0 = (blockIdx.x & 63) * 16;
    int tid = threadIdx.x;
    int w = tid >> 6, lane = tid & 63;
    int n = lane & 15, kc = lane >> 4;

    __shared__ __align__(16) _Float16 Xt[256 * 40];
    __shared__ __align__(16) _Float16 Bh[32 * 16 * 24];
    __shared__ __align__(16) _Float16 Wt[16 * 528];
    __shared__ float CN[2 * 16 * 16];

    if (tid < 32) {
        int s = tid >> 4, ll = tid & 15;
        const float* row = (s ? tc2 : tc1) + (size_t)(lg * 16 + ll) * 16;
        float e[16], m = -1e30f, sum = 0.f;
#pragma unroll
        for (int k = 0; k < 16; ++k) m = fmaxf(m, row[k]);
#pragma unroll
        for (int k = 0; k < 16; ++k) { e[k] = __expf(row[k] - m); sum += e[k]; }
        float r = 1.f / sum;
#pragma unroll
        for (int k = 0; k < 16; ++k) CN[s * 256 + ll * 16 + k] = e[k] * r;
    }
    __syncthreads();

    half8 cf1 = { 0, 0, 0, 0, 0, 0, 0, 0 };
    half8 cf2 = { 0, 0, 0, 0, 0, 0, 0, 0 };
    if (kc < 2) {
#pragma unroll
        for (int j = 0; j < 8; ++j) {
            cf1[j] = (_Float16)CN[0 * 256 + n * 16 + kc * 8 + j];
            cf2[j] = (_Float16)CN[1 * 256 + n * 16 + kc * 8 + j];
        }
    }

    f32x4 zf = { 0.f, 0.f, 0.f, 0.f };
    f32x4 aU[4], aV[4];
#pragma unroll
    for (int i = 0; i < 4; ++i) { aU[i] = zf; aV[i] = zf; }
    float nsqU[4] = { 0.f, 0.f, 0.f, 0.f };
    float nsqV[4] = { 0.f, 0.f, 0.f, 0.f };

    for (int it = 0; it < 16; ++it) {
        int d0 = it * 32;
#pragma unroll
        for (int p = 0; p < 8; ++p) {
            int r = p * 32 + (tid >> 3);
            int fj = tid & 7;
            int ll = r >> 4, b = r & 15;
            f32x4 v = *(const f32x4*)(
                x + ((size_t)(b * 128 + lg * 16 + ll) * 512 + d0 + fj * 4));
            half4 h = { (_Float16)v[0], (_Float16)v[1],
                        (_Float16)v[2], (_Float16)v[3] };
            *(half4*)(&Xt[r * 40 + fj * 4]) = h;
        }
#pragma unroll
        for (int p = 0; p < 8; ++p) {
            int idx = p * 256 + tid;
            int q = idx & 3, dd = (idx >> 2) & 31, k = idx >> 7;
            f32x4 v = *(const f32x4*)(
                wg + ((size_t)k * 512 + d0 + dd) * 1024 + f0 + q * 4);
#pragma unroll
            for (int j = 0; j < 4; ++j)
                Bh[(dd * 16 + q * 4 + j) * 24 + k] = (_Float16)v[j];
        }
        __syncthreads();
#pragma unroll
        for (int fl = 0; fl < 4; ++fl) {
            int f_l = w * 4 + fl;
#pragma unroll
            for (int dg = 0; dg < 2; ++dg) {
                half8 a = { 0, 0, 0, 0, 0, 0, 0, 0 };
                if (kc < 2)
                    a = *(const half8*)(&Bh[((dg * 16 + n) * 16 + f_l) * 24 + kc * 8]);
                f32x4 cw = MFMA_F16(a, cf1, zf, 0, 0, 0);
                nsqU[fl] += cw[0] * cw[0] + cw[1] * cw[1]
                          + cw[2] * cw[2] + cw[3] * cw[3];
                half4 h4 = { (_Float16)cw[0], (_Float16)cw[1],
                             (_Float16)cw[2], (_Float16)cw[3] };
                *(half4*)(&Wt[n * 528 + f_l * 32 + dg * 16 + kc * 4]) = h4;
            }
        }
        __syncthreads();
#pragma unroll
        for (int li = 0; li < 4; ++li) {
            int l = w * 4 + li;
            half8 xf = *(const half8*)(&Xt[(l * 16 + n) * 40 + kc * 8]);
            half8 wf = *(const half8*)(&Wt[l * 528 + n * 32 + kc * 8]);
            aU[li] = MFMA_F16(xf, wf, aU[li], 0, 0, 0);
        }
#pragma unroll
        for (int p = 0; p < 8; ++p) {
            int idx = p * 256 + tid;
            int q = idx & 3, dd = (idx >> 2) & 31, k = idx >> 7;
            f32x4 v = *(const f32x4*)(
                wu + ((size_t)k * 512 + d0 + dd) * 1024 + f0 + q * 4);
#pragma unroll
            for (int j = 0; j < 4; ++j)
                Bh[(dd * 16 + q * 4 + j) * 24 + k] = (_Float16)v[j];
        }
        __syncthreads();
#pragma unroll
        for (int fl = 0; fl < 4; ++fl) {
            int f_l = w * 4 + fl;
#pragma unroll
            for (int dg = 0; dg < 2; ++dg) {
                half8 a = { 0, 0, 0, 0, 0, 0, 0, 0 };
                if (kc < 2)
                    a = *(const half8*)(&Bh[((dg * 16 + n) * 16 + f_l) * 24 + kc * 8]);
                f32x4 cw = MFMA_F16(a, cf2, zf, 0, 0, 0);
                nsqV[fl] += cw[0] * cw[0] + cw[1] * cw[1]
                          + cw[2] * cw[2] + cw[3] * cw[3];
                half4 h4 = { (_Float16)cw[0], (_Float16)cw[1],
                             (_Float16)cw[2], (_Float16)cw[3] };
                *(half4*)(&Wt[n * 528 + f_l * 32 + dg * 16 + kc * 4]) = h4;
            }
        }
        __syncthreads();
#pragma unroll
        for (int li = 0; li < 4; ++li) {
            int l = w * 4 + li;
            half8 xf = *(const half8*)(&Xt[(l * 16 + n) * 40 + kc * 8]);
            half8 wf = *(const half8*)(&Wt[l * 528 + n * 32 + kc * 8]);
            aV[li] = MFMA_F16(xf, wf, aV[li], 0, 0, 0);
        }
        __syncthreads();
    }

#pragma unroll
    for (int fl = 0; fl < 4; ++fl) {
        float vU = nsqU[fl], vV = nsqV[fl];
        vU += __shfl_xor(vU, 16); vU += __shfl_xor(vU, 32);
        vV += __shfl_xor(vV, 16); vV += __shfl_xor(vV, 32);
        if (kc == 0) {
            CN[0 * 256 + n * 16 + w * 4 + fl] = vU;
            CN[1 * 256 + n * 16 + w * 4 + fl] = vV;
        }
    }
    __syncthreads();

    int f = f0 + n;
    float usv = fabsf(usp[f]);
    float vsv = fabsf(vsp[f]) * 22.627416997969522f;
#pragma unroll
    for (int li = 0; li < 4; ++li) {
        int lgl = lg * 16 + w * 4 + li;
        float r1 = 1.f / fmaxf(sqrtf(CN[0 * 256 + (w * 4 + li) * 16 + n]), 1e-12f);
        float r2 = 1.f / fmaxf(sqrtf(CN[1 * 256 + (w * 4 + li) * 16 + n]), 1e-12f);
#pragma unroll
        for (int i = 0; i < 4; ++i) {
            float u = aU[li][i] * r1;
            float v = aV[li][i] * r2;
            float zz = vsv * v;
            float sil = zz / (1.f + __expf(-zz));
            float h = sil * (usv * u);
            Hp[((size_t)lgl * 16 + kc * 4 + i) * 1024 + f] = (_Float16)h;
        }
    }
}

__global__ __launch_bounds__(256) void down_kernel(
    const float* __restrict__ wd, const float* __restrict__ tc3,
    const _Float16* __restrict__ Hp, float* __restrict__ out)
{
    int lg = blockIdx.x >> 5;
    int d0 = (blockIdx.x & 31) * 16;
    int tid = threadIdx.x;
    int w = tid >> 6, lane = tid & 63;
    int n = lane & 15, kc = lane >> 4;

    __shared__ __align__(16) _Float16 Ht[256 * 40];
    __shared__ __align__(16) _Float16 Bh[32 * 16 * 24];
    __shared__ __align__(16) _Float16 Wt[16 * 528];
    __shared__ float CN[16 * 16];

    if (tid < 16) {
        const float* row = tc3 + (size_t)(lg * 16 + tid) * 16;
        float e[16], m = -1e30f, sum = 0.f;
#pragma unroll
        for (int k = 0; k < 16; ++k) m = fmaxf(m, row[k]);
#pragma unroll
        for (int k = 0; k < 16; ++k) { e[k] = __expf(row[k] - m); sum += e[k]; }
        float r = 1.f / sum;
#pragma unroll
        for (int k = 0; k < 16; ++k) CN[tid * 16 + k] = e[k] * r;
    }
    __syncthreads();

    half8 cf3 = { 0, 0, 0, 0, 0, 0, 0, 0 };
    if (kc < 2) {
#pragma unroll
        for (int j = 0; j < 8; ++j)
            cf3[j] = (_Float16)CN[n * 16 + kc * 8 + j];
    }

    f32x4 zf = { 0.f, 0.f, 0.f, 0.f };
    f32x4 aO[4];
#pragma unroll
    for (int i = 0; i < 4; ++i) aO[i] = zf;
    float nsqD[4] = { 0.f, 0.f, 0.f, 0.f };

    for (int it = 0; it < 32; ++it) {
        int f0 = it * 32;
#pragma unroll
        for (int p = 0; p < 8; ++p) {
            int r = p * 32 + (tid >> 3);
            int hj = tid & 7;
            int ll = r >> 4, b = r & 15;
            half4 v = *(const half4*)(
                Hp + ((size_t)(lg * 16 + ll) * 16 + b) * 1024 + f0 + hj * 4);
            *(half4*)(&Ht[r * 40 + hj * 4]) = v;
        }
#pragma unroll
        for (int p = 0; p < 8; ++p) {
            int idx = p * 256 + tid;
            int q = idx & 3, ff = (idx >> 2) & 31, k = idx >> 7;
            f32x4 v = *(const f32x4*)(
                wd + ((size_t)k * 1024 + f0 + ff) * 512 + d0 + q * 4);
#pragma unroll
            for (int j = 0; j < 4; ++j)
                Bh[(ff * 16 + q * 4 + j) * 24 + k] = (_Float16)v[j];
        }
        __syncthreads();
#pragma unroll
        for (int dl = 0; dl < 4; ++dl) {
            int d_l = w * 4 + dl;
#pragma unroll
            for (int fg = 0; fg < 2; ++fg) {
                half8 a = { 0, 0, 0, 0, 0, 0, 0, 0 };
                if (kc < 2)
                    a = *(const half8*)(&Bh[((fg * 16 + n) * 16 + d_l) * 24 + kc * 8]);
                f32x4 cw = MFMA_F16(a, cf3, zf, 0, 0, 0);
                nsqD[dl] += cw[0] * cw[0] + cw[1] * cw[1]
                          + cw[2] * cw[2] + cw[3] * cw[3];
                half4 h4 = { (_Float16)cw[0], (_Float16)cw[1],
                             (_Float16)cw[2], (_Float16)cw[3] };
                *(half4*)(&Wt[n * 528 + d_l * 32 + fg * 16 + kc * 4]) = h4;
            }
        }
        __syncthreads();
#pragma unroll
        for (int li = 0; li < 4; ++li) {
            int l = w * 4 + li;
            half8 hf = *(const half8*)(&Ht[(l * 16 + n) * 40 + kc * 8]);
            half8 wf = *(const half8*)(&Wt[l * 528 + n * 32 + kc * 8]);
            aO[li] = MFMA_F16(hf, wf, aO[li], 0, 0, 0);
        }
        __syncthreads();
    }

#pragma unroll
    for (int dl = 0; dl < 4; ++dl) {
        float v = nsqD[dl];
        v += __shfl_xor(v, 16); v += __shfl_xor(v, 32);
        if (kc == 0) CN[n * 16 + w * 4 + dl] = v;
    }
    __syncthreads();

#pragma unroll
    for (int li = 0; li < 4; ++li) {
        int lgl = lg * 16 + w * 4 + li;
        float r3 = 1.f / fmaxf(sqrtf(CN[(w * 4 + li) * 16 + n]), 1e-12f);
#pragma unroll
        for (int i = 0; i < 4; ++i)
            out[((size_t)(kc * 4 + i) * 128 + lgl) * 512 + d0 + n] = aO[li][i] * r3;
    }
}

__global__ __launch_bounds__(128) void final_kernel(float* __restrict__ out)
{
    int rid = blockIdx.x;
    int t = threadIdx.x;
    f32x4 y = *(const f32x4*)(out + (size_t)rid * 512 + t * 4);
    float s = y[0] * y[0] + y[1] * y[1] + y[2] * y[2] + y[3] * y[3];
#pragma unroll
    for (int off = 32; off > 0; off >>= 1) s += __shfl_down(s, off);
    __shared__ float sred[2];
    if ((t & 63) == 0) sred[t >> 6] = s;
    __syncthreads();
    float rr = 1.f / fmaxf(sqrtf(sred[0] + sred[1]), 1e-12f);
    f32x4 o = { y[0] * rr, y[1] * rr, y[2] * rr, y[3] * rr };
    *(f32x4*)(out + (size_t)rid * 512 + t * 4) = o;
}

// ---------------------------------------------------------------------------
extern "C" void kernel_launch(void* const* d_in, const int* in_sizes, int n_in,
                              void* d_out, int out_size, void* d_ws, size_t ws_size,
                              hipStream_t stream)
{
    (void)in_sizes; (void)n_in; (void)out_size;
    const float* x   = (const float*)d_in[0];
    const float* wg  = (const float*)d_in[1];
    const float* wu  = (const float*)d_in[2];
    const float* wd  = (const float*)d_in[3];
    const float* tc1 = (const float*)d_in[4];
    const float* tc2 = (const float*)d_in[5];
    const float* tc3 = (const float*)d_in[6];
    const float* usp = (const float*)d_in[7];
    const float* vsp = (const float*)d_in[8];
    float* outp = (float*)d_out;
    char* ws = (char*)d_ws;

    if (ws_size >= WS_FAST) {
        _Float16* P1  = (_Float16*)(ws + OFF_P1);
        _Float16* P2  = (_Float16*)(ws + OFF_P2);
        _Float16* P3n = (_Float16*)(ws + OFF_P3n);  // 17..33 MiB (after Np)
        _Float16* XA  = (_Float16*)(ws + OFF_XA);   // 32..34 MiB
        _Float16* U2  = (_Float16*)(ws + OFF_U2);   // 34..38 MiB
        _Float16* S   = (_Float16*)(ws + OFF_S);    // 38..42 MiB
        float* Rp = (float*)(ws + OFF_P1);   // overlays P1 (dead after up)
        float* Np = (float*)(ws + OFF_P2);   // 16..17 MiB (P2 dead after up)
        prep_basis_all<<<dim3(512, 2), dim3(256), 0, stream>>>(
            wg, wu, wd, P1, P2, P3n, 0);                   // P1, P2
        prep_x<<<dim3(256), dim3(256), 0, stream>>>(x, XA);
        up_split<<<dim3(1024), dim3(256), 0, stream>>>(P1, P2, XA, tc1, tc2,
                                                       usp, vsp, U2, S);
        prep_basis_all<<<dim3(512, 1), dim3(256), 0, stream>>>(
            wg, wu, wd, P1, P2, P3n, 2);                   // P3 at 17 MiB
        down_fast<<<dim3(1024), dim3(256), 0, stream>>>(P3n, tc3, S, U2, Rp, Np);
        final_combine<<<dim3(2048), dim3(128), 0, stream>>>(Rp, Np, outp);
    } else {
        _Float16* Hp = (_Float16*)ws;
        up_kernel<<<dim3(512), dim3(256), 0, stream>>>(x, wg, wu, tc1, tc2,
                                                       usp, vsp, Hp);
        down_kernel<<<dim3(256), dim3(256), 0, stream>>>(wd, tc3, Hp, outp);
        final_kernel<<<dim3(2048), dim3(128), 0, stream>>>(outp);
    }
}